// Round 13
// baseline (3202.402 us; speedup 1.0000x reference)
//
#include <hip/hip_runtime.h>

#define B_ 256
#define S_ 128
#define F_ 512
#define H_ 1024
#define A_ 18
#define M_ (B_*S_)      // 32768 output rows (b*S+s)
#define G_ (4*H_)       // 4096 gate cols, permuted unit-major: p = unit*4 + {i,f,g,o}
#define CH_ 16          // timesteps per chunk
#define CR_ (B_*CH_)    // 4096 rows per chunk, row rg = b*CH_ + dt

typedef unsigned short u16;
typedef __attribute__((ext_vector_type(8))) _Float16 f16x8;  // 8 fp16 = 4 VGPR
typedef __attribute__((ext_vector_type(4))) _Float16 f16x4;
typedef __attribute__((ext_vector_type(4))) u16 u16x4;
typedef __attribute__((ext_vector_type(8))) short   s16x8;
typedef __attribute__((ext_vector_type(4))) float f32x4;
typedef __attribute__((ext_vector_type(4))) unsigned int u32x4;

__device__ __forceinline__ float bf2f(u16 u){
  union{unsigned int i; float f;} v; v.i=((unsigned int)u)<<16; return v.f;
}
__device__ __forceinline__ u16 f2bf(float f){
  unsigned int i=__float_as_uint(f);
  unsigned int r=(i+0x7fffu+((i>>16)&1u))>>16;   // RNE
  return (u16)r;
}
__device__ __forceinline__ u16 f2h(float f){
  _Float16 h=(_Float16)f;
  union{_Float16 h; u16 u;} v; v.h=h; return v.u;
}
// mode-aware scalar load of logical float element i (1: fp32, 0: bf16)
__device__ __forceinline__ float ldf(const void* p, size_t i, int m){
  return m ? ((const float*)p)[i] : bf2f(((const u16*)p)[i]);
}
// load 8 logical floats -> fp16x8. mode 0: bf16 src, 1: fp32 src, 2: raw fp16 src.
__device__ __forceinline__ f16x8 load8_h(const void* base, size_t off, int m){
  f16x8 v;
  if(m==2) return *(const f16x8*)((const u16*)base + off);
  if(m==1){
    const float* f=(const float*)base + off;
    float4 a=*(const float4*)f; float4 b=*(const float4*)(f+4);
    v[0]=(_Float16)a.x; v[1]=(_Float16)a.y; v[2]=(_Float16)a.z; v[3]=(_Float16)a.w;
    v[4]=(_Float16)b.x; v[5]=(_Float16)b.y; v[6]=(_Float16)b.z; v[7]=(_Float16)b.w;
    return v;
  }
  s16x8 w=*(const s16x8*)((const u16*)base + off);
#pragma unroll
  for(int k=0;k<8;k++) v[k]=(_Float16)bf2f((u16)w[k]);
  return v;
}

// ---- coherent (cross-XCD, LLC-routed) accesses: bypass L1+L2 via sc0 sc1.
__device__ __forceinline__ u32x4 load_c16(const void* p){
  u32x4 r;
  asm volatile("global_load_dwordx4 %0, %1, off sc0 sc1" : "=v"(r) : "v"(p));
  return r;
}
__device__ __forceinline__ void store_c2(u16* p, u16 v){
  unsigned int vv=v;
  asm volatile("global_store_short %0, %1, off sc0 sc1" :: "v"(p), "v"(vv) : "memory");
}
__device__ __forceinline__ int load_c4(const int* p){
  int r;
  asm volatile("global_load_dword %0, %1, off sc0 sc1" : "=v"(r) : "v"(p));
  return r;
}
__device__ __forceinline__ void store_c4(int* p, int v){
  asm volatile("global_store_dword %0, %1, off sc0 sc1" :: "v"(p), "v"(v) : "memory");
}

// ---- Stage ROWS x 64 fp16 tile into LDS [ROWS][64], XOR-swizzled 16B chunks (256-thr blocks).
// mode 2: global_load_lds direct (linear dest, inverse-swizzled per-lane src).
// MAP 0: src row = rowoff+r. MAP 1: p=rowoff+r -> (p&3)*H_+(p>>2). MAP 2: p -> (p>>4)*S_+t0+(p&15).
template<int ROWS, int MAP>
__device__ __forceinline__ void stage(const void* base, int mode, int lda, int k0,
                                      int rowoff, int t0, u16* lds, int tid){
  if(mode==2){
    constexpr int NI=(ROWS*8)/256;
    int wv=tid>>6, l=tid&63;
#pragma unroll
    for(int i=0;i<NI;i++){
      int s0=i*256+(wv<<6), s=s0+l;
      int r=s>>3, gc=(s&7)^(r&7);
      int p=rowoff+r, sr;
      if(MAP==0)      sr=p;
      else if(MAP==1) sr=(p&3)*H_+(p>>2);
      else            sr=(p>>4)*S_+t0+(p&15);
      const u16* src=(const u16*)base + (size_t)sr*lda + k0 + gc*8;
      u16* dst=lds + s0*8;             // wave-uniform; HW adds lane*16B
      __builtin_amdgcn_global_load_lds((const __attribute__((address_space(1))) unsigned int*)src,
                                       (__attribute__((address_space(3))) unsigned int*)dst,
                                       16, 0, 0);
    }
  } else {
#pragma unroll
    for(int s0=tid; s0<ROWS*8; s0+=256){
      int r=s0>>3, gc=s0&7, lc=gc^(r&7);
      int p=rowoff+r, sr;
      if(MAP==0)      sr=p;
      else if(MAP==1) sr=(p&3)*H_+(p>>2);
      else            sr=(p>>4)*S_+t0+(p&15);
      f16x8 v=load8_h(base, (size_t)sr*lda + k0 + gc*8, mode);
      *(f16x8*)(lds + r*64 + lc*8)=v;
    }
  }
}

// MFMA 16x16x32 fragment from swizzled LDS tile: lane -> row r0+(l&15), chunk kc+(l>>4), un-XOR.
__device__ __forceinline__ f16x8 frag_ld(const u16* lds, int r0, int kc, int lane){
  int r = r0 + (lane&15);
  int c = (kc + (lane>>4)) ^ (r&7);
  return *(const f16x8*)(lds + r*64 + c*8);
}

// ---- 128x128-tile GEMM: C = A * B^T + biasf. amode/bmode: <0 -> *flag, else literal.
// OUTMODE 0: relu+fp16. 1: fp32. 2: fp16 (no relu).
template<int AMAP, int BMAP, int OUTMODE>
__global__ __launch_bounds__(256,3) void gemm128(const void* A, const void* Bt, void* C,
    const float* __restrict__ biasf, const int* __restrict__ flag,
    int K, int lda, int ldb, int ldc, int t0, int amode, int bmode){
  int m=*flag;
  int am = amode<0 ? m : amode;
  int bm_ = bmode<0 ? m : bmode;
  __shared__ u16 As[128*64];
  __shared__ u16 Bs[128*64];
  int tid=threadIdx.x, lane=tid&63, w=tid>>6;
  int bm=blockIdx.y*128, bn=blockIdx.x*128;
  int wm=(w&1)*64, wn=(w>>1)*64;
  f32x4 acc[4][4];
#pragma unroll
  for(int i=0;i<4;i++)
#pragma unroll
    for(int j=0;j<4;j++) acc[i][j]=(f32x4)(0.f);
  for(int k0=0;k0<K;k0+=64){
    stage<128,AMAP>(A , am,  lda, k0, bm, t0, As, tid);
    stage<128,BMAP>(Bt, bm_, ldb, k0, bn, t0, Bs, tid);
    __syncthreads();
#pragma unroll
    for(int kk=0;kk<2;kk++){
      f16x8 af[4], bq[4];
#pragma unroll
      for(int i=0;i<4;i++) af[i]=frag_ld(As, wm+i*16, kk*4, lane);
#pragma unroll
      for(int j=0;j<4;j++) bq[j]=frag_ld(Bs, wn+j*16, kk*4, lane);
#pragma unroll
      for(int i=0;i<4;i++)
#pragma unroll
        for(int j=0;j<4;j++)
          acc[i][j]=__builtin_amdgcn_mfma_f32_16x16x32_f16(af[i],bq[j],acc[i][j],0,0,0);
    }
    __syncthreads();
  }
  int rl=lane>>4, cl=lane&15;
#pragma unroll
  for(int j=0;j<4;j++){
    int col=bn+wn+j*16+cl;
    float bb=biasf[col];
#pragma unroll
    for(int i=0;i<4;i++){
#pragma unroll
      for(int r=0;r<4;r++){
        int row=bm+wm+i*16+rl*4+r;
        float v=acc[i][j][r]+bb;
        if(OUTMODE==0){ v=fmaxf(v,0.f); ((u16*)C)[(size_t)row*ldc+col]=f2h(v); }
        else if(OUTMODE==2){ ((u16*)C)[(size_t)row*ldc+col]=f2h(v); }
        else { ((float*)C)[(size_t)row*ldc+col]=v; }
      }
    }
  }
}

// ---- persistent chunk-LSTM v9 = v8 + FUSED next-chunk xg GEMM in the latency slack.
// After the arrival-flag store each step, waves compute one dt-slice of NEXT chunk's xg
// (their own 32-batch x 128-col block): 64 MFMA, operands streamed from global (L2-hot:
// Wihp block-private 256KB, xc shared within group), +bias, 2x8B stores into xg2.
// No new barriers; gemm sits entirely off the inter-block critical path.
__global__ __launch_bounds__(512,2) void lstm_persist(u16* __restrict__ hh,
        const u16* __restrict__ Whhp, const u16* __restrict__ xgp,
        float* __restrict__ cst, int* __restrict__ cntc, int tbase,
        const u16* __restrict__ xcf, const u16* __restrict__ Wihp,
        const float* __restrict__ biasg, u16* __restrict__ xg2){
  __shared__ u16 As[16*2048];     // 64 KB: 16 k-tiles [32][64], XOR-swizzled
  __shared__ u16 hs[32*36];       // 2.3 KB h bounce [batch][unit], pad 36
  int tid=threadIdx.x, lane=tid&63, w=tid>>6;
  int grp=blockIdx.x&7, ci=blockIdx.x>>3;
  int bm=grp*32, bn=ci*128;
  int* flags = cntc + grp*64;
  bool dog = (xg2 != nullptr);

  // Whh slice -> 32 f16x8 (wave's 16 gate-cols x K=1024), pinned in AGPRs.
  f16x8 bw[32];
#pragma unroll
  for(int t=0;t<32;t++){
    int p = bn + w*16 + (lane&15);
    int k = t*32 + (lane>>4)*8;
    bw[t]=*(const f16x8*)(Whhp + (size_t)p*H_ + k);
  }
#pragma unroll
  for(int t=0;t<32;t++) asm volatile("" : "+a"(bw[t]));

  // lane cell mapping (swapped-D): batch col = lane&15 (+16 for acc1),
  // unit-local ul = w*4 + (lane>>4); gates = acc[0..3].
  int bb0=lane&15, bb1=16+(lane&15);
  int ul = w*4 + (lane>>4);
  int gu2 = (bn>>2) + ul;
  float c0=cst[(size_t)(bm+bb0)*H_+gu2];
  float c1=cst[(size_t)(bm+bb1)*H_+gu2];
  // coalesced-store assignment: thread -> (batch tid>>5, unit tid&31), and +512
  int sb0=tid>>5, su=tid&31, sb1=(tid+512)>>5;

  // fused-gemm lane pointers (constant over steps except +dt*H_)
  int p0 = bn + w*16 + (lane>>4)*4;
  const u16* wrow = Wihp + (size_t)(bn + w*16 + (lane&15))*H_ + (lane>>4)*8;
  const u16* xr0  = xcf + ((size_t)(bm+bb0)*S_ + tbase + CH_)*H_ + (lane>>4)*8;
  const u16* xr1  = xcf + ((size_t)(bm+bb1)*S_ + tbase + CH_)*H_ + (lane>>4)*8;
  float4 bias4; if(dog) bias4=*(const float4*)(biasg + p0);

  // xg prefetch for step 0
  size_t xoff0=((size_t)(bm+bb0)*CH_)*G_ + bn + w*16 + (lane>>4)*4;
  size_t xoff1=((size_t)(bm+bb1)*CH_)*G_ + bn + w*16 + (lane>>4)*4;
  f16x4 xga0=*(const f16x4*)(xgp + xoff0);
  f16x4 xga1=*(const f16x4*)(xgp + xoff1);

  for(int dt=0;dt<CH_;dt++){
    if(dt){
      // departure only: wave0 polls 32 flags (arrival stored at prev step's end)
      if(w==0){
        int target=tbase+dt;
        while(true){
          int v=load_c4(flags+(lane&31));
          asm volatile("s_waitcnt vmcnt(0)" ::: "memory");
          if(__all(v>=target)) break;
          __builtin_amdgcn_s_sleep(1);
        }
      }
      __syncthreads();
    }
    // stage h_prev[32][1024] (cached loads; safe: each hh addr read once/launch,
    // writes bypass L2, kernel-start buffer_inv cleared stale lines)
    {
      int slotPrev=(dt+CH_-1)&(CH_-1);
      const u16* hbase = hh + (size_t)slotPrev*H_;
      u32x4 tmp[8];
#pragma unroll
      for(int i=0;i<8;i++){
        int s=tid+i*512, kt=s>>8, r=(s>>3)&31, gc=s&7;
        tmp[i]=*(const u32x4*)(hbase + (size_t)(bm+r)*(CH_*H_) + kt*64 + gc*8);
      }
#pragma unroll
      for(int i=0;i<8;i++){
        int s=tid+i*512, kt=s>>8, r=(s>>3)&31, gc=s&7, lc=gc^(r&7);
        *(u32x4*)(As + kt*2048 + r*64 + lc*8)=tmp[i];
      }
    }
    __syncthreads();
    // LSTM MFMA: 4 independent chains (row-group x K-parity), 64 MFMA total
    f32x4 a0e=(f32x4)(0.f), a0o=(f32x4)(0.f), a1e=(f32x4)(0.f), a1o=(f32x4)(0.f);
#pragma unroll
    for(int kt=0;kt<16;kt++){
      f16x8 af0=frag_ld(As+kt*2048, 0,  0, lane);
      f16x8 af1=frag_ld(As+kt*2048, 16, 0, lane);
      a0e=__builtin_amdgcn_mfma_f32_16x16x32_f16(bw[2*kt],af0,a0e,0,0,0);
      a1e=__builtin_amdgcn_mfma_f32_16x16x32_f16(bw[2*kt],af1,a1e,0,0,0);
      f16x8 bf0=frag_ld(As+kt*2048, 0,  4, lane);
      f16x8 bf1=frag_ld(As+kt*2048, 16, 4, lane);
      a0o=__builtin_amdgcn_mfma_f32_16x16x32_f16(bw[2*kt+1],bf0,a0o,0,0,0);
      a1o=__builtin_amdgcn_mfma_f32_16x16x32_f16(bw[2*kt+1],bf1,a1o,0,0,0);
    }
    f32x4 A0=a0e+a0o, A1=a1e+a1o;
    // in-register elementwise: lane owns unit gu2 for batches bb0, bb1
    u16 h0w, h1w;
    {
      float ii=1.f/(1.f+__expf(-(A0[0]+(float)xga0[0])));
      float ff=1.f/(1.f+__expf(-(A0[1]+(float)xga0[1])));
      float gg=1.f-2.f/(__expf(2.f*(A0[2]+(float)xga0[2]))+1.f);
      float oo=1.f/(1.f+__expf(-(A0[3]+(float)xga0[3])));
      c0=ff*c0+ii*gg;
      float th=1.f-2.f/(__expf(2.f*c0)+1.f);
      h0w=f2h(oo*th);
    }
    {
      float ii=1.f/(1.f+__expf(-(A1[0]+(float)xga1[0])));
      float ff=1.f/(1.f+__expf(-(A1[1]+(float)xga1[1])));
      float gg=1.f-2.f/(__expf(2.f*(A1[2]+(float)xga1[2]))+1.f);
      float oo=1.f/(1.f+__expf(-(A1[3]+(float)xga1[3])));
      c1=ff*c1+ii*gg;
      float th=1.f-2.f/(__expf(2.f*c1)+1.f);
      h1w=f2h(oo*th);
    }
    // h bounce -> coalesced coherent store
    hs[bb0*36+ul]=h0w;
    hs[bb1*36+ul]=h1w;
    __syncthreads();
    store_c2(hh + ((size_t)(bm+sb0)*CH_+dt)*H_ + (bn>>2)+su, hs[sb0*36+su]);
    store_c2(hh + ((size_t)(bm+sb1)*CH_+dt)*H_ + (bn>>2)+su, hs[sb1*36+su]);
    // arrival: own h stores drained -> flag
    asm volatile("s_waitcnt vmcnt(0)" ::: "memory");
    __syncthreads();
    if(dt<CH_-1){
      if(tid==0) store_c4(flags+ci, tbase+dt+1);
      // xg prefetch for next step (issued before gemm so latency hides under it)
      xga0=*(const f16x4*)(xgp + xoff0 + (size_t)(dt+1)*G_);
      xga1=*(const f16x4*)(xgp + xoff1 + (size_t)(dt+1)*G_);
    }
    // ---- fused gemm slice (off critical path): xg2 rows (bm+bb)*CH_+dt, cols p0..p0+3
    if(dog){
      const u16* x0p = xr0 + (size_t)dt*H_;
      const u16* x1p = xr1 + (size_t)dt*H_;
      f32x4 g0=(f32x4)(0.f), g1=(f32x4)(0.f);
#pragma unroll
      for(int kt=0;kt<32;kt++){
        f16x8 aw=*(const f16x8*)(wrow + kt*32);
        f16x8 x0=*(const f16x8*)(x0p + kt*32);
        f16x8 x1=*(const f16x8*)(x1p + kt*32);
        g0=__builtin_amdgcn_mfma_f32_16x16x32_f16(aw,x0,g0,0,0,0);
        g1=__builtin_amdgcn_mfma_f32_16x16x32_f16(aw,x1,g1,0,0,0);
      }
      u16x4 o0,o1;
#pragma unroll
      for(int r=0;r<4;r++){
        o0[r]=f2h(g0[r]+bias4[r]);
        o1[r]=f2h(g1[r]+bias4[r]);
      }
      *(u16x4*)(xg2 + ((size_t)(bm+bb0)*CH_+dt)*G_ + p0)=o0;
      *(u16x4*)(xg2 + ((size_t)(bm+bb1)*CH_+dt)*G_ + p0)=o1;
    }
  }
  cst[(size_t)(bm+bb0)*H_+gu2]=c0;
  cst[(size_t)(bm+bb1)*H_+gu2]=c1;
}

// ---- fallback per-step LSTM (low-ws tier): gates = xg(fp16) + h_prev @ Whh(perm)^T.
__global__ __launch_bounds__(256,2) void lstm_step(u16* __restrict__ hh, int slotPrev, int dt,
        const void* __restrict__ Whh, const u16* __restrict__ xg,
        float* __restrict__ cst, const int* __restrict__ flag){
  int m=*flag;
  __shared__ u16 As[64*64];
  __shared__ u16 Bs[64*64];
  __shared__ float gs[64*64];
  int tid=threadIdx.x, lane=tid&63, w=tid>>6;
  int bm=blockIdx.y*64, bn=blockIdx.x*64;
  int wm=(w&1)*32, wn=(w>>1)*32;
  f32x4 acc[2][2];
#pragma unroll
  for(int i=0;i<2;i++)
#pragma unroll
    for(int j=0;j<2;j++) acc[i][j]=(f32x4)(0.f);
  for(int k0=0;k0<H_;k0+=64){
    stage<64,0>(hh + slotPrev*H_, 2, CH_*H_, k0, bm, 0, As, tid);
    stage<64,1>(Whh,              m, H_,     k0, bn, 0, Bs, tid);
    __syncthreads();
#pragma unroll
    for(int kk=0;kk<2;kk++){
      f16x8 af[2], bq[2];
#pragma unroll
      for(int i=0;i<2;i++) af[i]=frag_ld(As, wm+i*16, kk*4, lane);
#pragma unroll
      for(int j=0;j<2;j++) bq[j]=frag_ld(Bs, wn+j*16, kk*4, lane);
#pragma unroll
      for(int i=0;i<2;i++)
#pragma unroll
        for(int j=0;j<2;j++)
          acc[i][j]=__builtin_amdgcn_mfma_f32_16x16x32_f16(af[i],bq[j],acc[i][j],0,0,0);
    }
    __syncthreads();
  }
  int rl=lane>>4, cl=lane&15;
#pragma unroll
  for(int j=0;j<2;j++){
    int coll=wn+j*16+cl;
#pragma unroll
    for(int i=0;i<2;i++){
#pragma unroll
      for(int r=0;r<4;r++){
        int rowl=wm+i*16+rl*4+r;
        float xv=(float)((const _Float16*)xg)[((size_t)(bm+rowl)*CH_+dt)*G_ + bn+coll];
        gs[rowl*64+coll]=acc[i][j][r] + xv;
      }
    }
  }
  __syncthreads();
#pragma unroll
  for(int p=0;p<4;p++){
    int idx=p*256+tid;
    int rowl=idx>>4, u=idx&15;
    float4 gv = *(const float4*)&gs[rowl*64+u*4];
    float ii=1.f/(1.f+__expf(-gv.x));
    float ff=1.f/(1.f+__expf(-gv.y));
    float gg=1.f-2.f/(__expf(2.f*gv.z)+1.f);
    float oo=1.f/(1.f+__expf(-gv.w));
    int gb=bm+rowl;
    int gu=(bn>>2)+u;
    size_t ci=(size_t)gb*H_+gu;
    float cn=ff*cst[ci]+ii*gg;
    cst[ci]=cn;
    float th=1.f-2.f/(__expf(2.f*cn)+1.f);
    hh[(size_t)gb*(CH_*H_) + dt*H_ + gu]=f2h(oo*th);
  }
}

// ---- heads for one chunk: wave per row rg=b*CH_+dt; output gw=b*S+t0+dt.
__global__ __launch_bounds__(256,2) void heads_chunk(const u16* __restrict__ hh,
      const void* __restrict__ Wl, const void* __restrict__ Wv,
      const float* __restrict__ blf, const int* __restrict__ acts,
      void* __restrict__ out, const int* __restrict__ flag, int t0){
  int m=*flag;
  int rg = blockIdx.x*4 + (threadIdx.x>>6);
  int lane = threadIdx.x & 63;
  const u16* h = hh + (size_t)rg*H_;               // fp16, written via sc0sc1 -> read coherent
  u32x4 hv0=load_c16(h + lane*16);
  u32x4 hv1=load_c16(h + lane*16 + 8);
  f16x8 h0=__builtin_bit_cast(f16x8,hv0), h1=__builtin_bit_cast(f16x8,hv1);
  float hv[16];
#pragma unroll
  for(int k=0;k<8;k++){ hv[k]=(float)h0[k]; hv[8+k]=(float)h1[k]; }
  float dots[19];
#pragma unroll
  for(int j=0;j<19;j++){
    const void* wrow = (j<18) ? Wl : Wv;
    size_t roff = (j<18) ? (size_t)j*H_ : 0;
    float wv_[16];
    if(m){
      const float* f=(const float*)wrow + roff + lane*16;
      float4 a=*(const float4*)f, b=*(const float4*)(f+4), c=*(const float4*)(f+8), d=*(const float4*)(f+12);
      wv_[0]=a.x;wv_[1]=a.y;wv_[2]=a.z;wv_[3]=a.w; wv_[4]=b.x;wv_[5]=b.y;wv_[6]=b.z;wv_[7]=b.w;
      wv_[8]=c.x;wv_[9]=c.y;wv_[10]=c.z;wv_[11]=c.w; wv_[12]=d.x;wv_[13]=d.y;wv_[14]=d.z;wv_[15]=d.w;
    } else {
      const u16* ub=(const u16*)wrow + roff + lane*16;
      s16x8 w0=*(const s16x8*)ub, w1=*(const s16x8*)(ub+8);
#pragma unroll
      for(int k=0;k<8;k++){ wv_[k]=bf2f((u16)w0[k]); wv_[8+k]=bf2f((u16)w1[k]); }
    }
    float d=0.f;
#pragma unroll
    for(int k=0;k<16;k++) d += hv[k]*wv_[k];
#pragma unroll
    for(int mm=1;mm<64;mm<<=1) d += __shfl_xor(d, mm, 64);
    dots[j]=d;
  }
  float lg[18];
#pragma unroll
  for(int j=0;j<18;j++) lg[j]=dots[j]+blf[j];
  float value=dots[18]+blf[18];
  float mx=lg[0];
#pragma unroll
  for(int j=1;j<18;j++) mx=fmaxf(mx,lg[j]);
  float se=0.f, s1=0.f;
#pragma unroll
  for(int j=0;j<18;j++){ float e=__expf(lg[j]-mx); se+=e; s1+=e*(lg[j]-mx); }
  float lse=__logf(se);
  int b=rg>>4, dt=rg&(CH_-1);
  int gw = b*S_ + t0 + dt;
  int a=acts[gw];
  float la=0.f;
#pragma unroll
  for(int j=0;j<18;j++) la = (j==a) ? lg[j] : la;
  float lp=la-mx-lse;
  float ent=lse - s1/se;
  if(lane==0){
    if(m){
      ((float*)out)[gw]=lp; ((float*)out)[M_+gw]=ent; ((float*)out)[2*M_+gw]=value;
    } else {
      ((u16*)out)[gw]=f2bf(lp); ((u16*)out)[M_+gw]=f2bf(ent); ((u16*)out)[2*M_+gw]=f2bf(value);
    }
  }
}

// ---- dtype detect
__global__ void detect(const u16* __restrict__ obs_w, int* __restrict__ flag){
  __shared__ float red[256];
  float mx=0.f;
  for(int i=threadIdx.x;i<4096;i+=256) mx=fmaxf(mx,fabsf(bf2f(obs_w[i])));
  red[threadIdx.x]=mx; __syncthreads();
  for(int s=128;s>0;s>>=1){
    if(threadIdx.x<s) red[threadIdx.x]=fmaxf(red[threadIdx.x],red[threadIdx.x+s]);
    __syncthreads();
  }
  if(threadIdx.x==0) *flag=(red[0]>1e4f)?1:0;
}

// ---- prep: biases, c state, h seed (fp16, slot CH_-1), zero barrier flags.
__global__ void prep(const void* bih, const void* bhh, const void* b1, const void* bl, const void* bv,
                     const void* cx, const void* hx,
                     float* biasg, float* b1f, float* blf, float* cst, u16* hh,
                     int* cnt, const int* __restrict__ flag){
  int m=*flag;
  size_t i=(size_t)blockIdx.x*256+threadIdx.x;
  if(i<G_){ size_t rm=(i&3)*H_+(i>>2); biasg[i]=ldf(bih,rm,m)+ldf(bhh,rm,m); return; }
  i-=G_;
  if(i<H_){ b1f[i]=ldf(b1,i,m); return; }
  i-=H_;
  if(i<19){ blf[i]=(i<18)?ldf(bl,i,m):ldf(bv,0,m); return; }
  i-=19;
  if(i<512){ cnt[i]=0; return; }
  i-=512;
  if(i<(size_t)B_*H_){ cst[i]=ldf(cx,i,m); return; }
  i-=(size_t)B_*H_;
  if(i<(size_t)B_*H_){
    size_t b=i>>10, k=i&1023;
    hh[b*(CH_*H_) + (CH_-1)*H_ + k]=f2h(ldf(hx,i,m));
  }
}

// ---- weight pre-conversion to fp16 (exact from bf16), gate-permuted for Wih/Whh.
__global__ void convw(const void* W1, const void* Wih, const void* Whh,
                      u16* W1h, u16* Wihp, u16* Whhp, const int* __restrict__ flag){
  int m=*flag;
  size_t i=((size_t)blockIdx.x*256+threadIdx.x)*8;
  const size_t n1=(size_t)H_*F_, n2=(size_t)G_*H_;
  if(i<n1){ *(f16x8*)(W1h+i)=load8_h(W1,i,m); return; }
  i-=n1;
  if(i<n2){ size_t p=i>>10, c=i&1023; size_t sr=(p&3)*H_+(p>>2);
            *(f16x8*)(Wihp+i)=load8_h(Wih, sr*H_+c, m); return; }
  i-=n2;
  if(i<n2){ size_t p=i>>10, c=i&1023; size_t sr=(p&3)*H_+(p>>2);
            *(f16x8*)(Whhp+i)=load8_h(Whh, sr*H_+c, m); return; }
}
__global__ void convobs(const void* obs, u16* obsh, const int* __restrict__ flag){
  int m=*flag;
  size_t i=((size_t)blockIdx.x*256+threadIdx.x)*8;
  if(i<(size_t)M_*F_) *(f16x8*)(obsh+i)=load8_h(obs,i,m);
}

extern "C" void kernel_launch(void* const* d_in, const int* in_sizes, int n_in,
                              void* d_out, int out_size, void* d_ws, size_t ws_size,
                              hipStream_t stream){
  const void* obs=d_in[0];
  const void* hx =d_in[1];
  const void* cx =d_in[2];
  const int* acts=(const int*)d_in[3];
  const void* W1 =d_in[4];
  const void* b1 =d_in[5];
  const void* Wih=d_in[6];
  const void* bih=d_in[7];
  const void* Whh=d_in[8];
  const void* bhh=d_in[9];
  const void* Wv =d_in[10];
  const void* bv =d_in[11];
  const void* Wl =d_in[12];
  const void* bl =d_in[13];

  char* w=(char*)d_ws;
  auto alloc=[&](size_t n){ char* p=w; w+=((n+255)&~(size_t)255); return p; };
  int*   flag =(int*)alloc(4);
  int*   cnt  =(int*)alloc(512*4);                 // 8 groups x 64 flag slots (32 used)
  float* biasg=(float*)alloc((size_t)G_*4);
  float* b1f  =(float*)alloc((size_t)H_*4);
  float* blf  =(float*)alloc(32*4);
  float* cst  =(float*)alloc((size_t)B_*H_*4);     // 1 MB fp32 c
  u16*   hh   =(u16*)alloc((size_t)B_*CH_*H_*2);   // 8 MB fp16 h history [B][16][H]
  u16*   xc   =(u16*)alloc((size_t)CR_*H_*2);      // 8 MB fp16 x chunk
  u16*   xg   =(u16*)alloc((size_t)CR_*G_*2);      // 32 MB fp16 xg chunk A
  // tiers
  size_t nW=((size_t)H_*F_ + 2*(size_t)G_*H_)*2 + 768;
  bool pathW = ((size_t)(w-(char*)d_ws) + nW) <= ws_size;
  u16 *W1h=0,*Wihp=0,*Whhp=0;
  if(pathW){ W1h=(u16*)alloc((size_t)H_*F_*2); Wihp=(u16*)alloc((size_t)G_*H_*2); Whhp=(u16*)alloc((size_t)G_*H_*2); }
  size_t nXC=(size_t)M_*H_*2 + 256;
  bool pathXC = pathW && (((size_t)(w-(char*)d_ws) + nXC) <= ws_size);
  u16* xcf=0; if(pathXC) xcf=(u16*)alloc((size_t)M_*H_*2);
  size_t nF=(size_t)CR_*G_*2 + 256;
  bool pathF = pathXC && (((size_t)(w-(char*)d_ws) + nF) <= ws_size);
  u16* xgB=0; if(pathF) xgB=(u16*)alloc((size_t)CR_*G_*2);   // xg chunk B (ping-pong)
  size_t nO=(size_t)M_*F_*2 + 256;
  bool pathO = pathXC && (((size_t)(w-(char*)d_ws) + nO) <= ws_size);
  u16* obsh=0; if(pathO) obsh=(u16*)alloc((size_t)M_*F_*2);

  detect<<<1,256,0,stream>>>((const u16*)obs, flag);
  {
    int total=G_+H_+19+512+B_*H_+B_*H_;
    prep<<<(total+255)/256,256,0,stream>>>(bih,bhh,b1,bl,bv,cx,hx, biasg,b1f,blf,cst,hh,cnt, flag);
  }
  if(pathW){
    size_t n=((size_t)H_*F_+2*(size_t)G_*H_)/8;
    convw<<<(int)((n+255)/256),256,0,stream>>>(W1,Wih,Whh, W1h,Wihp,Whhp, flag);
  }
  if(pathO){
    size_t n=(size_t)M_*F_/8;
    convobs<<<(int)((n+255)/256),256,0,stream>>>(obs, obsh, flag);
  }
  if(pathXC){
    gemm128<0,0,0><<<dim3(H_/128, M_/128),256,0,stream>>>(
        pathO?(const void*)obsh:obs, pathW?(const void*)W1h:W1, xcf, b1f, flag,
        F_, F_, F_, H_, 0, pathO?2:-1, pathW?2:-1);
  }

  const int NC=S_/CH_;
  for(int c=0;c<NC;c++){
    int t0=c*CH_;
    u16* xgcur = (pathF && (c&1)) ? xgB : xg;
    u16* xgnxt = (pathF && !(c&1)) ? xgB : xg;
    if(!pathXC){
      gemm128<2,0,0><<<dim3(H_/128, CR_/128),256,0,stream>>>(
          obs, pathW?(const void*)W1h:W1, xc, b1f, flag, F_, F_, F_, H_, t0, -1, pathW?2:-1);
    }
    // standalone xg gemm: every chunk unless fused (then only chunk 0)
    if(!pathF || c==0){
      if(pathXC)
        gemm128<2,0,2><<<dim3(G_/128, CR_/128),256,0,stream>>>(
            xcf, Wihp, xgcur, biasg, flag, H_, H_, H_, G_, t0, 2, 2);
      else if(pathW)
        gemm128<0,0,2><<<dim3(G_/128, CR_/128),256,0,stream>>>(
            xc, Wihp, xgcur, biasg, flag, H_, H_, H_, G_, 0, 2, 2);
      else
        gemm128<0,1,2><<<dim3(G_/128, CR_/128),256,0,stream>>>(
            xc, Wih, xgcur, biasg, flag, H_, H_, H_, G_, 0, 2, -1);
    }

    if(pathW)
      lstm_persist<<<256,512,0,stream>>>(hh, Whhp, xgcur, cst, cnt, t0,
          xcf, Wihp, biasg, (pathF && c<NC-1) ? xgnxt : (u16*)nullptr);
    else
      for(int dt=0;dt<CH_;dt++)
        lstm_step<<<dim3(G_/64, B_/64),256,0,stream>>>(hh, (dt+CH_-1)&(CH_-1), dt, Whh, xgcur, cst, flag);

    heads_chunk<<<dim3(CR_/4),256,0,stream>>>(hh, Wl, Wv, blf, acts, d_out, flag, t0);
  }
}

// Round 14
// 1238.460 us; speedup vs baseline: 2.5858x; 2.5858x over previous
//
#include <hip/hip_runtime.h>

#define B_ 256
#define S_ 128
#define SP1 (S_+1)
#define F_ 512
#define H_ 1024
#define A_ 18
#define M_ (B_*S_)      // 32768 output rows (b*S+s)
#define G_ (4*H_)       // 4096 gate cols, permuted unit-major: p = unit*4 + {i,f,g,o}
#define CH_ 16          // timesteps per chunk
#define CR_ (B_*CH_)    // 4096 rows per chunk, row rg = b*CH_ + dt

typedef unsigned short u16;
typedef __attribute__((ext_vector_type(8))) _Float16 f16x8;  // 8 fp16 = 4 VGPR
typedef __attribute__((ext_vector_type(4))) _Float16 f16x4;
typedef __attribute__((ext_vector_type(8))) short   s16x8;
typedef __attribute__((ext_vector_type(4))) float f32x4;
typedef __attribute__((ext_vector_type(4))) unsigned int u32x4;

__device__ __forceinline__ float bf2f(u16 u){
  union{unsigned int i; float f;} v; v.i=((unsigned int)u)<<16; return v.f;
}
__device__ __forceinline__ u16 f2bf(float f){
  unsigned int i=__float_as_uint(f);
  unsigned int r=(i+0x7fffu+((i>>16)&1u))>>16;   // RNE
  return (u16)r;
}
__device__ __forceinline__ u16 f2h(float f){
  _Float16 h=(_Float16)f;
  union{_Float16 h; u16 u;} v; v.h=h; return v.u;
}
// mode-aware scalar load of logical float element i (1: fp32, 0: bf16)
__device__ __forceinline__ float ldf(const void* p, size_t i, int m){
  return m ? ((const float*)p)[i] : bf2f(((const u16*)p)[i]);
}
// load 8 logical floats -> fp16x8. mode 0: bf16 src, 1: fp32 src, 2: raw fp16 src.
__device__ __forceinline__ f16x8 load8_h(const void* base, size_t off, int m){
  f16x8 v;
  if(m==2) return *(const f16x8*)((const u16*)base + off);
  if(m==1){
    const float* f=(const float*)base + off;
    float4 a=*(const float4*)f; float4 b=*(const float4*)(f+4);
    v[0]=(_Float16)a.x; v[1]=(_Float16)a.y; v[2]=(_Float16)a.z; v[3]=(_Float16)a.w;
    v[4]=(_Float16)b.x; v[5]=(_Float16)b.y; v[6]=(_Float16)b.z; v[7]=(_Float16)b.w;
    return v;
  }
  s16x8 w=*(const s16x8*)((const u16*)base + off);
#pragma unroll
  for(int k=0;k<8;k++) v[k]=(_Float16)bf2f((u16)w[k]);
  return v;
}

// ---- coherent (cross-XCD, LLC-routed) accesses: bypass L1+L2 via sc0 sc1.
__device__ __forceinline__ u32x4 load_c16(const void* p){
  u32x4 r;
  asm volatile("global_load_dwordx4 %0, %1, off sc0 sc1" : "=v"(r) : "v"(p));
  return r;
}
__device__ __forceinline__ void store_c2(u16* p, u16 v){
  unsigned int vv=v;
  asm volatile("global_store_short %0, %1, off sc0 sc1" :: "v"(p), "v"(vv) : "memory");
}
__device__ __forceinline__ int load_c4(const int* p){
  int r;
  asm volatile("global_load_dword %0, %1, off sc0 sc1" : "=v"(r) : "v"(p));
  return r;
}
__device__ __forceinline__ void store_c4(int* p, int v){
  asm volatile("global_store_dword %0, %1, off sc0 sc1" :: "v"(p), "v"(v) : "memory");
}

// ---- store-flag group barrier (32 blocks): arrival = own-flag store (monotonic target),
// departure = wave-0 parallel poll of 32 flags.
__device__ __forceinline__ void bar_flags32(int* flags, int target, int gi, int lane, int w){
  asm volatile("s_waitcnt vmcnt(0)" ::: "memory");   // own h stores at LLC
  __syncthreads();
  if(w==0){
    if(lane==0) store_c4(flags+gi, target);
    while(true){
      int v=load_c4(flags+(lane&31));
      asm volatile("s_waitcnt vmcnt(0)" ::: "memory");
      if(__all(v>=target)) break;
      __builtin_amdgcn_s_sleep(1);
    }
  }
  __syncthreads();
}

// ---- Stage ROWS x 64 fp16 tile into LDS [ROWS][64], XOR-swizzled 16B chunks (256-thr blocks).
// mode 2: global_load_lds direct (linear dest, inverse-swizzled per-lane src).
// MAP 0: src row = rowoff+r. MAP 1: p=rowoff+r -> (p&3)*H_+(p>>2). MAP 2: p -> (p>>4)*S_+t0+(p&15).
template<int ROWS, int MAP>
__device__ __forceinline__ void stage(const void* base, int mode, int lda, int k0,
                                      int rowoff, int t0, u16* lds, int tid){
  if(mode==2){
    constexpr int NI=(ROWS*8)/256;
    int wv=tid>>6, l=tid&63;
#pragma unroll
    for(int i=0;i<NI;i++){
      int s0=i*256+(wv<<6), s=s0+l;
      int r=s>>3, gc=(s&7)^(r&7);
      int p=rowoff+r, sr;
      if(MAP==0)      sr=p;
      else if(MAP==1) sr=(p&3)*H_+(p>>2);
      else            sr=(p>>4)*S_+t0+(p&15);
      const u16* src=(const u16*)base + (size_t)sr*lda + k0 + gc*8;
      u16* dst=lds + s0*8;             // wave-uniform; HW adds lane*16B
      __builtin_amdgcn_global_load_lds((const __attribute__((address_space(1))) unsigned int*)src,
                                       (__attribute__((address_space(3))) unsigned int*)dst,
                                       16, 0, 0);
    }
  } else {
#pragma unroll
    for(int s0=tid; s0<ROWS*8; s0+=256){
      int r=s0>>3, gc=s0&7, lc=gc^(r&7);
      int p=rowoff+r, sr;
      if(MAP==0)      sr=p;
      else if(MAP==1) sr=(p&3)*H_+(p>>2);
      else            sr=(p>>4)*S_+t0+(p&15);
      f16x8 v=load8_h(base, (size_t)sr*lda + k0 + gc*8, mode);
      *(f16x8*)(lds + r*64 + lc*8)=v;
    }
  }
}

// MFMA 16x16x32 fragment from swizzled LDS tile: lane -> row r0+(l&15), chunk kc+(l>>4), un-XOR.
__device__ __forceinline__ f16x8 frag_ld(const u16* lds, int r0, int kc, int lane){
  int r = r0 + (lane&15);
  int c = (kc + (lane>>4)) ^ (r&7);
  return *(const f16x8*)(lds + r*64 + c*8);
}

// ---- 128x128-tile GEMM: C = A * B^T + biasf. amode/bmode: <0 -> *flag, else literal.
// OUTMODE 0: relu+fp16. 1: fp32. 2: fp16 (no relu).
template<int AMAP, int BMAP, int OUTMODE>
__global__ __launch_bounds__(256,3) void gemm128(const void* A, const void* Bt, void* C,
    const float* __restrict__ biasf, const int* __restrict__ flag,
    int K, int lda, int ldb, int ldc, int t0, int amode, int bmode){
  int m=*flag;
  int am = amode<0 ? m : amode;
  int bm_ = bmode<0 ? m : bmode;
  __shared__ u16 As[128*64];
  __shared__ u16 Bs[128*64];
  int tid=threadIdx.x, lane=tid&63, w=tid>>6;
  int bm=blockIdx.y*128, bn=blockIdx.x*128;
  int wm=(w&1)*64, wn=(w>>1)*64;
  f32x4 acc[4][4];
#pragma unroll
  for(int i=0;i<4;i++)
#pragma unroll
    for(int j=0;j<4;j++) acc[i][j]=(f32x4)(0.f);
  for(int k0=0;k0<K;k0+=64){
    stage<128,AMAP>(A , am,  lda, k0, bm, t0, As, tid);
    stage<128,BMAP>(Bt, bm_, ldb, k0, bn, t0, Bs, tid);
    __syncthreads();
#pragma unroll
    for(int kk=0;kk<2;kk++){
      f16x8 af[4], bq[4];
#pragma unroll
      for(int i=0;i<4;i++) af[i]=frag_ld(As, wm+i*16, kk*4, lane);
#pragma unroll
      for(int j=0;j<4;j++) bq[j]=frag_ld(Bs, wn+j*16, kk*4, lane);
#pragma unroll
      for(int i=0;i<4;i++)
#pragma unroll
        for(int j=0;j<4;j++)
          acc[i][j]=__builtin_amdgcn_mfma_f32_16x16x32_f16(af[i],bq[j],acc[i][j],0,0,0);
    }
    __syncthreads();
  }
  int rl=lane>>4, cl=lane&15;
#pragma unroll
  for(int j=0;j<4;j++){
    int col=bn+wn+j*16+cl;
    float bb=biasf[col];
#pragma unroll
    for(int i=0;i<4;i++){
#pragma unroll
      for(int r=0;r<4;r++){
        int row=bm+wm+i*16+rl*4+r;
        float v=acc[i][j][r]+bb;
        if(OUTMODE==0){ v=fmaxf(v,0.f); ((u16*)C)[(size_t)row*ldc+col]=f2h(v); }
        else if(OUTMODE==2){ ((u16*)C)[(size_t)row*ldc+col]=f2h(v); }
        else { ((float*)C)[(size_t)row*ldc+col]=v; }
      }
    }
  }
}

// ---- persistent chunk-LSTM (r11-verified structure; hh now FULL [B][S+1][H], seed slot 0,
// step t writes slot t+1). Cached stage loads (each hh addr read once/launch; writes bypass
// L2 sc0sc1; kernel-start buffer_inv clears stale lines). Split-half stage/MFMA overlap.
// Whh pinned in AGPRs. Grid 256 (1/CU), 512 thr. grp=blockIdx&7 (bm=grp*32), ci=blockIdx>>3.
__global__ __launch_bounds__(512,2) void lstm_persist(u16* __restrict__ hh,
        const u16* __restrict__ Whhp, const u16* __restrict__ xgp,
        float* __restrict__ cst, int* __restrict__ cntc, int tbase){
  __shared__ u16 As[16*2048];     // 64 KB: 16 k-tiles [32][64], XOR-swizzled
  __shared__ float gs[32*132];    // 16.9 KB, stride 132
  int tid=threadIdx.x, lane=tid&63, w=tid>>6;
  int grp=blockIdx.x&7, ci=blockIdx.x>>3;
  int bm=grp*32, bn=ci*128;
  int* flags = cntc + grp*64;

  // Whh slice -> 32 f16x8 (wave's 16 cols x K=1024), pinned in AGPRs.
  f16x8 bw[32];
#pragma unroll
  for(int t=0;t<32;t++){
    int p = bn + w*16 + (lane&15);
    int k = t*32 + (lane>>4)*8;
    bw[t]=*(const f16x8*)(Whhp + (size_t)p*H_ + k);
  }
#pragma unroll
  for(int t=0;t<32;t++) asm volatile("" : "+a"(bw[t]));

  // cells: 32 rows x 32 units = 1024; thread owns (rl0,u0) and (rl1,u0).
  int rl0=tid>>5, rl1=(tid+512)>>5, u0=tid&31;
  int gu=(bn>>2)+u0;
  float c0=cst[(size_t)(bm+rl0)*H_+gu];
  float c1=cst[(size_t)(bm+rl1)*H_+gu];

  for(int dt=0;dt<CH_;dt++){
    // xg prefetch (fp16, cached) — independent of h, issued BEFORE the barrier
    f16x4 xv0=*(const f16x4*)(xgp + ((size_t)(bm+rl0)*CH_+dt)*G_ + bn + u0*4);
    f16x4 xv1=*(const f16x4*)(xgp + ((size_t)(bm+rl1)*CH_+dt)*G_ + bn + u0*4);
    if(dt) bar_flags32(flags, tbase+dt, ci, lane, w);
    const u16* hbase = hh + (size_t)(tbase+dt)*H_;   // read slot tbase+dt
    // ---- half 1: stage k-tiles 0-7 (cached loads -> regs -> LDS swizzled)
    {
      u32x4 tmp[4];
#pragma unroll
      for(int i=0;i<4;i++){
        int s=tid+i*512, kt=s>>8, r=(s>>3)&31, gc=s&7;
        tmp[i]=*(const u32x4*)(hbase + (size_t)(bm+r)*(SP1*H_) + kt*64 + gc*8);
      }
#pragma unroll
      for(int i=0;i<4;i++){
        int s=tid+i*512, kt=s>>8, r=(s>>3)&31, gc=s&7, lc=gc^(r&7);
        *(u32x4*)(As + kt*2048 + r*64 + lc*8)=tmp[i];
      }
    }
    __syncthreads();
    // ---- issue half-2 loads; MFMA on half 1 while they fly
    u32x4 tmp2[4];
#pragma unroll
    for(int i=0;i<4;i++){
      int s=tid+(i+4)*512, kt=s>>8, r=(s>>3)&31, gc=s&7;
      tmp2[i]=*(const u32x4*)(hbase + (size_t)(bm+r)*(SP1*H_) + kt*64 + gc*8);
    }
    f32x4 acc0=(f32x4)(0.f), acc1=(f32x4)(0.f);
#pragma unroll
    for(int t=0;t<16;t++){
      int kt=t>>1, kk=t&1;
      f16x8 af0=frag_ld(As+kt*2048, 0,  kk*4, lane);
      f16x8 af1=frag_ld(As+kt*2048, 16, kk*4, lane);
      acc0=__builtin_amdgcn_mfma_f32_16x16x32_f16(af0,bw[t],acc0,0,0,0);
      acc1=__builtin_amdgcn_mfma_f32_16x16x32_f16(af1,bw[t],acc1,0,0,0);
    }
#pragma unroll
    for(int i=0;i<4;i++){
      int s=tid+(i+4)*512, kt=s>>8, r=(s>>3)&31, gc=s&7, lc=gc^(r&7);
      *(u32x4*)(As + kt*2048 + r*64 + lc*8)=tmp2[i];
    }
    __syncthreads();
    // ---- MFMA on half 2
#pragma unroll
    for(int t=16;t<32;t++){
      int kt=t>>1, kk=t&1;
      f16x8 af0=frag_ld(As+kt*2048, 0,  kk*4, lane);
      f16x8 af1=frag_ld(As+kt*2048, 16, kk*4, lane);
      acc0=__builtin_amdgcn_mfma_f32_16x16x32_f16(af0,bw[t],acc0,0,0,0);
      acc1=__builtin_amdgcn_mfma_f32_16x16x32_f16(af1,bw[t],acc1,0,0,0);
    }
    // gates -> gs (single pass); C/D: col=lane&15, row=(lane>>4)*4+r
#pragma unroll
    for(int r=0;r<4;r++){
      gs[(   (lane>>4)*4+r)*132 + w*16+(lane&15)]=acc0[r];
      gs[(16+(lane>>4)*4+r)*132 + w*16+(lane&15)]=acc1[r];
    }
    __syncthreads();
    // elementwise (2 cells/thread); coherent h store to slot tbase+dt+1
    {
      float4 gv=*(const float4*)&gs[rl0*132+u0*4];
      float ii=1.f/(1.f+__expf(-(gv.x+(float)xv0[0])));
      float ff=1.f/(1.f+__expf(-(gv.y+(float)xv0[1])));
      float gg=1.f-2.f/(__expf(2.f*(gv.z+(float)xv0[2]))+1.f);
      float oo=1.f/(1.f+__expf(-(gv.w+(float)xv0[3])));
      c0=ff*c0+ii*gg;
      float th=1.f-2.f/(__expf(2.f*c0)+1.f);
      store_c2(hh + ((size_t)(bm+rl0)*SP1 + tbase+dt+1)*H_ + gu, f2h(oo*th));
    }
    {
      float4 gv=*(const float4*)&gs[rl1*132+u0*4];
      float ii=1.f/(1.f+__expf(-(gv.x+(float)xv1[0])));
      float ff=1.f/(1.f+__expf(-(gv.y+(float)xv1[1])));
      float gg=1.f-2.f/(__expf(2.f*(gv.z+(float)xv1[2]))+1.f);
      float oo=1.f/(1.f+__expf(-(gv.w+(float)xv1[3])));
      c1=ff*c1+ii*gg;
      float th=1.f-2.f/(__expf(2.f*c1)+1.f);
      store_c2(hh + ((size_t)(bm+rl1)*SP1 + tbase+dt+1)*H_ + gu, f2h(oo*th));
    }
    // next bar_flags32's __syncthreads orders gs reads vs next step's writes
  }
  cst[(size_t)(bm+rl0)*H_+gu]=c0;
  cst[(size_t)(bm+rl1)*H_+gu]=c1;
}

// ---- fallback per-step LSTM (low-ws tier): gates = xg(fp16) + h_prev @ Whh(perm)^T.
__global__ __launch_bounds__(256,2) void lstm_step(u16* __restrict__ hh, int slotAbs, int dt,
        const void* __restrict__ Whh, const u16* __restrict__ xg,
        float* __restrict__ cst, const int* __restrict__ flag){
  int m=*flag;
  __shared__ u16 As[64*64];
  __shared__ u16 Bs[64*64];
  __shared__ float gs[64*64];
  int tid=threadIdx.x, lane=tid&63, w=tid>>6;
  int bm=blockIdx.y*64, bn=blockIdx.x*64;
  int wm=(w&1)*32, wn=(w>>1)*32;
  f32x4 acc[2][2];
#pragma unroll
  for(int i=0;i<2;i++)
#pragma unroll
    for(int j=0;j<2;j++) acc[i][j]=(f32x4)(0.f);
  for(int k0=0;k0<H_;k0+=64){
    stage<64,0>(hh + (size_t)slotAbs*H_, 2, SP1*H_, k0, bm, 0, As, tid);
    stage<64,1>(Whh,                     m, H_,     k0, bn, 0, Bs, tid);
    __syncthreads();
#pragma unroll
    for(int kk=0;kk<2;kk++){
      f16x8 af[2], bq[2];
#pragma unroll
      for(int i=0;i<2;i++) af[i]=frag_ld(As, wm+i*16, kk*4, lane);
#pragma unroll
      for(int j=0;j<2;j++) bq[j]=frag_ld(Bs, wn+j*16, kk*4, lane);
#pragma unroll
      for(int i=0;i<2;i++)
#pragma unroll
        for(int j=0;j<2;j++)
          acc[i][j]=__builtin_amdgcn_mfma_f32_16x16x32_f16(af[i],bq[j],acc[i][j],0,0,0);
    }
    __syncthreads();
  }
  int rl=lane>>4, cl=lane&15;
#pragma unroll
  for(int j=0;j<2;j++){
    int coll=wn+j*16+cl;
#pragma unroll
    for(int i=0;i<2;i++){
#pragma unroll
      for(int r=0;r<4;r++){
        int rowl=wm+i*16+rl*4+r;
        float xv=(float)((const _Float16*)xg)[((size_t)(bm+rowl)*CH_+dt)*G_ + bn+coll];
        gs[rowl*64+coll]=acc[i][j][r] + xv;
      }
    }
  }
  __syncthreads();
#pragma unroll
  for(int p=0;p<4;p++){
    int idx=p*256+tid;
    int rowl=idx>>4, u=idx&15;
    float4 gv = *(const float4*)&gs[rowl*64+u*4];
    float ii=1.f/(1.f+__expf(-gv.x));
    float ff=1.f/(1.f+__expf(-gv.y));
    float gg=1.f-2.f/(__expf(2.f*gv.z)+1.f);
    float oo=1.f/(1.f+__expf(-gv.w));
    int gb=bm+rowl;
    int gu=(bn>>2)+u;
    size_t ci=(size_t)gb*H_+gu;
    float cn=ff*cst[ci]+ii*gg;
    cst[ci]=cn;
    float th=1.f-2.f/(__expf(2.f*cn)+1.f);
    hh[((size_t)gb*SP1 + slotAbs+1)*H_ + gu]=f2h(oo*th);
  }
}

// ---- heads over ALL timesteps: one dispatch, wave per rg=b*S+t; h at hh slot t+1.
__global__ __launch_bounds__(256,2) void heads_full(const u16* __restrict__ hh,
      const void* __restrict__ Wl, const void* __restrict__ Wv,
      const float* __restrict__ blf, const int* __restrict__ acts,
      void* __restrict__ out, const int* __restrict__ flag){
  int m=*flag;
  int rg = blockIdx.x*4 + (threadIdx.x>>6);        // 0..M_-1
  int lane = threadIdx.x & 63;
  int b=rg>>7, t=rg&(S_-1);
  const u16* h = hh + ((size_t)b*SP1 + t+1)*H_;    // fp16, sc0sc1-written -> coherent read
  u32x4 hv0=load_c16(h + lane*16);
  u32x4 hv1=load_c16(h + lane*16 + 8);
  f16x8 h0=__builtin_bit_cast(f16x8,hv0), h1=__builtin_bit_cast(f16x8,hv1);
  float hv[16];
#pragma unroll
  for(int k=0;k<8;k++){ hv[k]=(float)h0[k]; hv[8+k]=(float)h1[k]; }
  float dots[19];
#pragma unroll
  for(int j=0;j<19;j++){
    const void* wrow = (j<18) ? Wl : Wv;
    size_t roff = (j<18) ? (size_t)j*H_ : 0;
    float wv_[16];
    if(m){
      const float* f=(const float*)wrow + roff + lane*16;
      float4 a=*(const float4*)f, b2=*(const float4*)(f+4), c=*(const float4*)(f+8), d=*(const float4*)(f+12);
      wv_[0]=a.x;wv_[1]=a.y;wv_[2]=a.z;wv_[3]=a.w; wv_[4]=b2.x;wv_[5]=b2.y;wv_[6]=b2.z;wv_[7]=b2.w;
      wv_[8]=c.x;wv_[9]=c.y;wv_[10]=c.z;wv_[11]=c.w; wv_[12]=d.x;wv_[13]=d.y;wv_[14]=d.z;wv_[15]=d.w;
    } else {
      const u16* ub=(const u16*)wrow + roff + lane*16;
      s16x8 w0=*(const s16x8*)ub, w1=*(const s16x8*)(ub+8);
#pragma unroll
      for(int k=0;k<8;k++){ wv_[k]=bf2f((u16)w0[k]); wv_[8+k]=bf2f((u16)w1[k]); }
    }
    float d=0.f;
#pragma unroll
    for(int k=0;k<16;k++) d += hv[k]*wv_[k];
#pragma unroll
    for(int mm=1;mm<64;mm<<=1) d += __shfl_xor(d, mm, 64);
    dots[j]=d;
  }
  float lg[18];
#pragma unroll
  for(int j=0;j<18;j++) lg[j]=dots[j]+blf[j];
  float value=dots[18]+blf[18];
  float mx=lg[0];
#pragma unroll
  for(int j=1;j<18;j++) mx=fmaxf(mx,lg[j]);
  float se=0.f, s1=0.f;
#pragma unroll
  for(int j=0;j<18;j++){ float e=__expf(lg[j]-mx); se+=e; s1+=e*(lg[j]-mx); }
  float lse=__logf(se);
  int a=acts[rg];
  float la=0.f;
#pragma unroll
  for(int j=0;j<18;j++) la = (j==a) ? lg[j] : la;
  float lp=la-mx-lse;
  float ent=lse - s1/se;
  if(lane==0){
    if(m){
      ((float*)out)[rg]=lp; ((float*)out)[M_+rg]=ent; ((float*)out)[2*M_+rg]=value;
    } else {
      ((u16*)out)[rg]=f2bf(lp); ((u16*)out)[M_+rg]=f2bf(ent); ((u16*)out)[2*M_+rg]=f2bf(value);
    }
  }
}

// ---- dtype detect
__global__ void detect(const u16* __restrict__ obs_w, int* __restrict__ flag){
  __shared__ float red[256];
  float mx=0.f;
  for(int i=threadIdx.x;i<4096;i+=256) mx=fmaxf(mx,fabsf(bf2f(obs_w[i])));
  red[threadIdx.x]=mx; __syncthreads();
  for(int s=128;s>0;s>>=1){
    if(threadIdx.x<s) red[threadIdx.x]=fmaxf(red[threadIdx.x],red[threadIdx.x+s]);
    __syncthreads();
  }
  if(threadIdx.x==0) *flag=(red[0]>1e4f)?1:0;
}

// ---- prep: biases, c state, h seed (fp16, slot 0), zero barrier flags.
__global__ void prep(const void* bih, const void* bhh, const void* b1, const void* bl, const void* bv,
                     const void* cx, const void* hx,
                     float* biasg, float* b1f, float* blf, float* cst, u16* hh,
                     int* cnt, const int* __restrict__ flag){
  int m=*flag;
  size_t i=(size_t)blockIdx.x*256+threadIdx.x;
  if(i<G_){ size_t rm=(i&3)*H_+(i>>2); biasg[i]=ldf(bih,rm,m)+ldf(bhh,rm,m); return; }
  i-=G_;
  if(i<H_){ b1f[i]=ldf(b1,i,m); return; }
  i-=H_;
  if(i<19){ blf[i]=(i<18)?ldf(bl,i,m):ldf(bv,0,m); return; }
  i-=19;
  if(i<512){ cnt[i]=0; return; }
  i-=512;
  if(i<(size_t)B_*H_){ cst[i]=ldf(cx,i,m); return; }
  i-=(size_t)B_*H_;
  if(i<(size_t)B_*H_){
    size_t b=i>>10, k=i&1023;
    hh[b*(SP1*H_) + k]=f2h(ldf(hx,i,m));   // seed at slot 0
  }
}

// ---- weight pre-conversion to fp16 (exact from bf16), gate-permuted for Wih/Whh.
__global__ void convw(const void* W1, const void* Wih, const void* Whh,
                      u16* W1h, u16* Wihp, u16* Whhp, const int* __restrict__ flag){
  int m=*flag;
  size_t i=((size_t)blockIdx.x*256+threadIdx.x)*8;
  const size_t n1=(size_t)H_*F_, n2=(size_t)G_*H_;
  if(i<n1){ *(f16x8*)(W1h+i)=load8_h(W1,i,m); return; }
  i-=n1;
  if(i<n2){ size_t p=i>>10, c=i&1023; size_t sr=(p&3)*H_+(p>>2);
            *(f16x8*)(Wihp+i)=load8_h(Wih, sr*H_+c, m); return; }
  i-=n2;
  if(i<n2){ size_t p=i>>10, c=i&1023; size_t sr=(p&3)*H_+(p>>2);
            *(f16x8*)(Whhp+i)=load8_h(Whh, sr*H_+c, m); return; }
}
__global__ void convobs(const void* obs, u16* obsh, const int* __restrict__ flag){
  int m=*flag;
  size_t i=((size_t)blockIdx.x*256+threadIdx.x)*8;
  if(i<(size_t)M_*F_) *(f16x8*)(obsh+i)=load8_h(obs,i,m);
}

extern "C" void kernel_launch(void* const* d_in, const int* in_sizes, int n_in,
                              void* d_out, int out_size, void* d_ws, size_t ws_size,
                              hipStream_t stream){
  const void* obs=d_in[0];
  const void* hx =d_in[1];
  const void* cx =d_in[2];
  const int* acts=(const int*)d_in[3];
  const void* W1 =d_in[4];
  const void* b1 =d_in[5];
  const void* Wih=d_in[6];
  const void* bih=d_in[7];
  const void* Whh=d_in[8];
  const void* bhh=d_in[9];
  const void* Wv =d_in[10];
  const void* bv =d_in[11];
  const void* Wl =d_in[12];
  const void* bl =d_in[13];

  char* w=(char*)d_ws;
  auto alloc=[&](size_t n){ char* p=w; w+=((n+255)&~(size_t)255); return p; };
  int*   flag =(int*)alloc(4);
  int*   cnt  =(int*)alloc(512*4);                 // 8 groups x 64 flag slots (32 used)
  float* biasg=(float*)alloc((size_t)G_*4);
  float* b1f  =(float*)alloc((size_t)H_*4);
  float* blf  =(float*)alloc(32*4);
  float* cst  =(float*)alloc((size_t)B_*H_*4);     // 1 MB fp32 c
  u16*   hh   =(u16*)alloc((size_t)B_*SP1*H_*2);   // 67.6 MB fp16 full h history [B][S+1][H]
  u16*   xc   =(u16*)alloc((size_t)CR_*H_*2);      // 8 MB fp16 x chunk
  u16*   xg   =(u16*)alloc((size_t)CR_*G_*2);      // 32 MB fp16 xg chunk
  // tiers
  size_t nW=((size_t)H_*F_ + 2*(size_t)G_*H_)*2 + 768;
  bool pathW = ((size_t)(w-(char*)d_ws) + nW) <= ws_size;
  u16 *W1h=0,*Wihp=0,*Whhp=0;
  if(pathW){ W1h=(u16*)alloc((size_t)H_*F_*2); Wihp=(u16*)alloc((size_t)G_*H_*2); Whhp=(u16*)alloc((size_t)G_*H_*2); }
  size_t nXC=(size_t)M_*H_*2 + 256;
  bool pathXC = pathW && (((size_t)(w-(char*)d_ws) + nXC) <= ws_size);
  u16* xcf=0; if(pathXC) xcf=(u16*)alloc((size_t)M_*H_*2);
  size_t nO=(size_t)M_*F_*2 + 256;
  bool pathO = pathXC && (((size_t)(w-(char*)d_ws) + nO) <= ws_size);
  u16* obsh=0; if(pathO) obsh=(u16*)alloc((size_t)M_*F_*2);

  detect<<<1,256,0,stream>>>((const u16*)obs, flag);
  {
    int total=G_+H_+19+512+B_*H_+B_*H_;
    prep<<<(total+255)/256,256,0,stream>>>(bih,bhh,b1,bl,bv,cx,hx, biasg,b1f,blf,cst,hh,cnt, flag);
  }
  if(pathW){
    size_t n=((size_t)H_*F_+2*(size_t)G_*H_)/8;
    convw<<<(int)((n+255)/256),256,0,stream>>>(W1,Wih,Whh, W1h,Wihp,Whhp, flag);
  }
  if(pathO){
    size_t n=(size_t)M_*F_/8;
    convobs<<<(int)((n+255)/256),256,0,stream>>>(obs, obsh, flag);
  }
  if(pathXC){
    gemm128<0,0,0><<<dim3(H_/128, M_/128),256,0,stream>>>(
        pathO?(const void*)obsh:obs, pathW?(const void*)W1h:W1, xcf, b1f, flag,
        F_, F_, F_, H_, 0, pathO?2:-1, pathW?2:-1);
  }

  const int NC=S_/CH_;
  for(int c=0;c<NC;c++){
    int t0=c*CH_;
    if(!pathXC){
      gemm128<2,0,0><<<dim3(H_/128, CR_/128),256,0,stream>>>(
          obs, pathW?(const void*)W1h:W1, xc, b1f, flag, F_, F_, F_, H_, t0, -1, pathW?2:-1);
    }
    if(pathXC)
      gemm128<2,0,2><<<dim3(G_/128, CR_/128),256,0,stream>>>(
          xcf, Wihp, xg, biasg, flag, H_, H_, H_, G_, t0, 2, 2);
    else if(pathW)
      gemm128<0,0,2><<<dim3(G_/128, CR_/128),256,0,stream>>>(
          xc, Wihp, xg, biasg, flag, H_, H_, H_, G_, 0, 2, 2);
    else
      gemm128<0,1,2><<<dim3(G_/128, CR_/128),256,0,stream>>>(
          xc, Wih, xg, biasg, flag, H_, H_, H_, G_, 0, 2, -1);

    if(pathW)
      lstm_persist<<<256,512,0,stream>>>(hh, Whhp, xg, cst, cnt, t0);
    else
      for(int dt=0;dt<CH_;dt++)
        lstm_step<<<dim3(G_/64, B_/64),256,0,stream>>>(hh, t0+dt, dt, Whh, xg, cst, flag);
  }

  heads_full<<<dim3(M_/4),256,0,stream>>>(hh, Wl, Wv, blf, acts, d_out, flag);
}

// Round 15
// 1107.122 us; speedup vs baseline: 2.8925x; 1.1186x over previous
//
#include <hip/hip_runtime.h>

#define B_ 256
#define S_ 128
#define SP1 (S_+1)
#define F_ 512
#define H_ 1024
#define A_ 18
#define M_ (B_*S_)      // 32768 output rows (b*S+s)
#define G_ (4*H_)       // 4096 gate cols, permuted unit-major: p = unit*4 + {i,f,g,o}
#define CH_ 16          // timesteps per chunk
#define CR_ (B_*CH_)    // 4096 rows per chunk

typedef unsigned short u16;
typedef __attribute__((ext_vector_type(8))) _Float16 f16x8;  // 8 fp16 = 4 VGPR
typedef __attribute__((ext_vector_type(4))) _Float16 f16x4;
typedef __attribute__((ext_vector_type(8))) short   s16x8;
typedef __attribute__((ext_vector_type(4))) float f32x4;
typedef __attribute__((ext_vector_type(4))) unsigned int u32x4;

__device__ __forceinline__ float bf2f(u16 u){
  union{unsigned int i; float f;} v; v.i=((unsigned int)u)<<16; return v.f;
}
__device__ __forceinline__ u16 f2bf(float f){
  unsigned int i=__float_as_uint(f);
  unsigned int r=(i+0x7fffu+((i>>16)&1u))>>16;   // RNE
  return (u16)r;
}
__device__ __forceinline__ u16 f2h(float f){
  _Float16 h=(_Float16)f;
  union{_Float16 h; u16 u;} v; v.h=h; return v.u;
}
// mode-aware scalar load of logical float element i (1: fp32, 0: bf16)
__device__ __forceinline__ float ldf(const void* p, size_t i, int m){
  return m ? ((const float*)p)[i] : bf2f(((const u16*)p)[i]);
}
// load 8 logical floats -> fp16x8. mode 0: bf16 src, 1: fp32 src, 2: raw fp16 src.
__device__ __forceinline__ f16x8 load8_h(const void* base, size_t off, int m){
  f16x8 v;
  if(m==2) return *(const f16x8*)((const u16*)base + off);
  if(m==1){
    const float* f=(const float*)base + off;
    float4 a=*(const float4*)f; float4 b=*(const float4*)(f+4);
    v[0]=(_Float16)a.x; v[1]=(_Float16)a.y; v[2]=(_Float16)a.z; v[3]=(_Float16)a.w;
    v[4]=(_Float16)b.x; v[5]=(_Float16)b.y; v[6]=(_Float16)b.z; v[7]=(_Float16)b.w;
    return v;
  }
  s16x8 w=*(const s16x8*)((const u16*)base + off);
#pragma unroll
  for(int k=0;k<8;k++) v[k]=(_Float16)bf2f((u16)w[k]);
  return v;
}

// ---- coherent (cross-XCD, LLC-routed) accesses: bypass L1+L2 via sc0 sc1.
__device__ __forceinline__ void store_c2(u16* p, u16 v){
  unsigned int vv=v;
  asm volatile("global_store_short %0, %1, off sc0 sc1" :: "v"(p), "v"(vv) : "memory");
}
__device__ __forceinline__ int load_c4(const int* p){
  int r;
  asm volatile("global_load_dword %0, %1, off sc0 sc1" : "=v"(r) : "v"(p));
  return r;
}
__device__ __forceinline__ void store_c4(int* p, int v){
  asm volatile("global_store_dword %0, %1, off sc0 sc1" :: "v"(p), "v"(v) : "memory");
}

// ---- store-flag group barrier (32 blocks)
__device__ __forceinline__ void bar_flags32(int* flags, int target, int gi, int lane, int w){
  asm volatile("s_waitcnt vmcnt(0)" ::: "memory");   // own h stores at LLC
  __syncthreads();
  if(w==0){
    if(lane==0) store_c4(flags+gi, target);
    while(true){
      int v=load_c4(flags+(lane&31));
      asm volatile("s_waitcnt vmcnt(0)" ::: "memory");
      if(__all(v>=target)) break;
      __builtin_amdgcn_s_sleep(1);
    }
  }
  __syncthreads();
}

// ---- Stage ROWS x 64 fp16 tile into LDS [ROWS][64], XOR-swizzled 16B chunks (256-thr blocks).
// mode 2: global_load_lds direct. MAP 0: row=rowoff+r. MAP 1: gate-permute. MAP 2: obs rows.
template<int ROWS, int MAP>
__device__ __forceinline__ void stage(const void* base, int mode, int lda, int k0,
                                      int rowoff, int t0, u16* lds, int tid){
  if(mode==2){
    constexpr int NI=(ROWS*8)/256;
    int wv=tid>>6, l=tid&63;
#pragma unroll
    for(int i=0;i<NI;i++){
      int s0=i*256+(wv<<6), s=s0+l;
      int r=s>>3, gc=(s&7)^(r&7);
      int p=rowoff+r, sr;
      if(MAP==0)      sr=p;
      else if(MAP==1) sr=(p&3)*H_+(p>>2);
      else            sr=(p>>4)*S_+t0+(p&15);
      const u16* src=(const u16*)base + (size_t)sr*lda + k0 + gc*8;
      u16* dst=lds + s0*8;             // wave-uniform; HW adds lane*16B
      __builtin_amdgcn_global_load_lds((const __attribute__((address_space(1))) unsigned int*)src,
                                       (__attribute__((address_space(3))) unsigned int*)dst,
                                       16, 0, 0);
    }
  } else {
#pragma unroll
    for(int s0=tid; s0<ROWS*8; s0+=256){
      int r=s0>>3, gc=s0&7, lc=gc^(r&7);
      int p=rowoff+r, sr;
      if(MAP==0)      sr=p;
      else if(MAP==1) sr=(p&3)*H_+(p>>2);
      else            sr=(p>>4)*S_+t0+(p&15);
      f16x8 v=load8_h(base, (size_t)sr*lda + k0 + gc*8, mode);
      *(f16x8*)(lds + r*64 + lc*8)=v;
    }
  }
}

// MFMA 16x16x32 fragment from swizzled LDS tile: lane -> row r0+(l&15), chunk kc+(l>>4), un-XOR.
__device__ __forceinline__ f16x8 frag_ld(const u16* lds, int r0, int kc, int lane){
  int r = r0 + (lane&15);
  int c = (kc + (lane>>4)) ^ (r&7);
  return *(const f16x8*)(lds + r*64 + c*8);
}

// ---- 128x128-tile GEMM: C = A * B^T + biasf. amode/bmode: <0 -> *flag, else literal.
// OUTMODE 0: relu+fp16. 1: fp32. 2: fp16 (no relu).
template<int AMAP, int BMAP, int OUTMODE>
__global__ __launch_bounds__(256,3) void gemm128(const void* A, const void* Bt, void* C,
    const float* __restrict__ biasf, const int* __restrict__ flag,
    int K, int lda, int ldb, int ldc, int t0, int amode, int bmode){
  int m=*flag;
  int am = amode<0 ? m : amode;
  int bm_ = bmode<0 ? m : bmode;
  __shared__ u16 As[128*64];
  __shared__ u16 Bs[128*64];
  int tid=threadIdx.x, lane=tid&63, w=tid>>6;
  int bm=blockIdx.y*128, bn=blockIdx.x*128;
  int wm=(w&1)*64, wn=(w>>1)*64;
  f32x4 acc[4][4];
#pragma unroll
  for(int i=0;i<4;i++)
#pragma unroll
    for(int j=0;j<4;j++) acc[i][j]=(f32x4)(0.f);
  for(int k0=0;k0<K;k0+=64){
    stage<128,AMAP>(A , am,  lda, k0, bm, t0, As, tid);
    stage<128,BMAP>(Bt, bm_, ldb, k0, bn, t0, Bs, tid);
    __syncthreads();
#pragma unroll
    for(int kk=0;kk<2;kk++){
      f16x8 af[4], bq[4];
#pragma unroll
      for(int i=0;i<4;i++) af[i]=frag_ld(As, wm+i*16, kk*4, lane);
#pragma unroll
      for(int j=0;j<4;j++) bq[j]=frag_ld(Bs, wn+j*16, kk*4, lane);
#pragma unroll
      for(int i=0;i<4;i++)
#pragma unroll
        for(int j=0;j<4;j++)
          acc[i][j]=__builtin_amdgcn_mfma_f32_16x16x32_f16(af[i],bq[j],acc[i][j],0,0,0);
    }
    __syncthreads();
  }
  int rl=lane>>4, cl=lane&15;
#pragma unroll
  for(int j=0;j<4;j++){
    int col=bn+wn+j*16+cl;
    float bb=biasf[col];
#pragma unroll
    for(int i=0;i<4;i++){
#pragma unroll
      for(int r=0;r<4;r++){
        int row=bm+wm+i*16+rl*4+r;
        float v=acc[i][j][r]+bb;
        if(OUTMODE==0){ v=fmaxf(v,0.f); ((u16*)C)[(size_t)row*ldc+col]=f2h(v); }
        else if(OUTMODE==2){ ((u16*)C)[(size_t)row*ldc+col]=f2h(v); }
        else { ((float*)C)[(size_t)row*ldc+col]=v; }
      }
    }
  }
}

// ---- persistent chunk-LSTM (r11-verified; hh FULL [B][S+1][H], seed slot 0, step t -> t+1).
__global__ __launch_bounds__(512,2) void lstm_persist(u16* __restrict__ hh,
        const u16* __restrict__ Whhp, const u16* __restrict__ xgp,
        float* __restrict__ cst, int* __restrict__ cntc, int tbase){
  __shared__ u16 As[16*2048];     // 64 KB: 16 k-tiles [32][64], XOR-swizzled
  __shared__ float gs[32*132];    // 16.9 KB, stride 132
  int tid=threadIdx.x, lane=tid&63, w=tid>>6;
  int grp=blockIdx.x&7, ci=blockIdx.x>>3;
  int bm=grp*32, bn=ci*128;
  int* flags = cntc + grp*64;

  f16x8 bw[32];
#pragma unroll
  for(int t=0;t<32;t++){
    int p = bn + w*16 + (lane&15);
    int k = t*32 + (lane>>4)*8;
    bw[t]=*(const f16x8*)(Whhp + (size_t)p*H_ + k);
  }
#pragma unroll
  for(int t=0;t<32;t++) asm volatile("" : "+a"(bw[t]));

  int rl0=tid>>5, rl1=(tid+512)>>5, u0=tid&31;
  int gu=(bn>>2)+u0;
  float c0=cst[(size_t)(bm+rl0)*H_+gu];
  float c1=cst[(size_t)(bm+rl1)*H_+gu];

  for(int dt=0;dt<CH_;dt++){
    f16x4 xv0=*(const f16x4*)(xgp + ((size_t)(bm+rl0)*CH_+dt)*G_ + bn + u0*4);
    f16x4 xv1=*(const f16x4*)(xgp + ((size_t)(bm+rl1)*CH_+dt)*G_ + bn + u0*4);
    if(dt) bar_flags32(flags, tbase+dt, ci, lane, w);
    const u16* hbase = hh + (size_t)(tbase+dt)*H_;   // read slot tbase+dt
    {
      u32x4 tmp[4];
#pragma unroll
      for(int i=0;i<4;i++){
        int s=tid+i*512, kt=s>>8, r=(s>>3)&31, gc=s&7;
        tmp[i]=*(const u32x4*)(hbase + (size_t)(bm+r)*(SP1*H_) + kt*64 + gc*8);
      }
#pragma unroll
      for(int i=0;i<4;i++){
        int s=tid+i*512, kt=s>>8, r=(s>>3)&31, gc=s&7, lc=gc^(r&7);
        *(u32x4*)(As + kt*2048 + r*64 + lc*8)=tmp[i];
      }
    }
    __syncthreads();
    u32x4 tmp2[4];
#pragma unroll
    for(int i=0;i<4;i++){
      int s=tid+(i+4)*512, kt=s>>8, r=(s>>3)&31, gc=s&7;
      tmp2[i]=*(const u32x4*)(hbase + (size_t)(bm+r)*(SP1*H_) + kt*64 + gc*8);
    }
    f32x4 acc0=(f32x4)(0.f), acc1=(f32x4)(0.f);
#pragma unroll
    for(int t=0;t<16;t++){
      int kt=t>>1, kk=t&1;
      f16x8 af0=frag_ld(As+kt*2048, 0,  kk*4, lane);
      f16x8 af1=frag_ld(As+kt*2048, 16, kk*4, lane);
      acc0=__builtin_amdgcn_mfma_f32_16x16x32_f16(af0,bw[t],acc0,0,0,0);
      acc1=__builtin_amdgcn_mfma_f32_16x16x32_f16(af1,bw[t],acc1,0,0,0);
    }
#pragma unroll
    for(int i=0;i<4;i++){
      int s=tid+(i+4)*512, kt=s>>8, r=(s>>3)&31, gc=s&7, lc=gc^(r&7);
      *(u32x4*)(As + kt*2048 + r*64 + lc*8)=tmp2[i];
    }
    __syncthreads();
#pragma unroll
    for(int t=16;t<32;t++){
      int kt=t>>1, kk=t&1;
      f16x8 af0=frag_ld(As+kt*2048, 0,  kk*4, lane);
      f16x8 af1=frag_ld(As+kt*2048, 16, kk*4, lane);
      acc0=__builtin_amdgcn_mfma_f32_16x16x32_f16(af0,bw[t],acc0,0,0,0);
      acc1=__builtin_amdgcn_mfma_f32_16x16x32_f16(af1,bw[t],acc1,0,0,0);
    }
#pragma unroll
    for(int r=0;r<4;r++){
      gs[(   (lane>>4)*4+r)*132 + w*16+(lane&15)]=acc0[r];
      gs[(16+(lane>>4)*4+r)*132 + w*16+(lane&15)]=acc1[r];
    }
    __syncthreads();
    {
      float4 gv=*(const float4*)&gs[rl0*132+u0*4];
      float ii=1.f/(1.f+__expf(-(gv.x+(float)xv0[0])));
      float ff=1.f/(1.f+__expf(-(gv.y+(float)xv0[1])));
      float gg=1.f-2.f/(__expf(2.f*(gv.z+(float)xv0[2]))+1.f);
      float oo=1.f/(1.f+__expf(-(gv.w+(float)xv0[3])));
      c0=ff*c0+ii*gg;
      float th=1.f-2.f/(__expf(2.f*c0)+1.f);
      store_c2(hh + ((size_t)(bm+rl0)*SP1 + tbase+dt+1)*H_ + gu, f2h(oo*th));
    }
    {
      float4 gv=*(const float4*)&gs[rl1*132+u0*4];
      float ii=1.f/(1.f+__expf(-(gv.x+(float)xv1[0])));
      float ff=1.f/(1.f+__expf(-(gv.y+(float)xv1[1])));
      float gg=1.f-2.f/(__expf(2.f*(gv.z+(float)xv1[2]))+1.f);
      float oo=1.f/(1.f+__expf(-(gv.w+(float)xv1[3])));
      c1=ff*c1+ii*gg;
      float th=1.f-2.f/(__expf(2.f*c1)+1.f);
      store_c2(hh + ((size_t)(bm+rl1)*SP1 + tbase+dt+1)*H_ + gu, f2h(oo*th));
    }
  }
  cst[(size_t)(bm+rl0)*H_+gu]=c0;
  cst[(size_t)(bm+rl1)*H_+gu]=c1;
}

// ---- fallback per-step LSTM (low-ws tier)
__global__ __launch_bounds__(256,2) void lstm_step(u16* __restrict__ hh, int slotAbs, int dt,
        const void* __restrict__ Whh, const u16* __restrict__ xg,
        float* __restrict__ cst, const int* __restrict__ flag){
  int m=*flag;
  __shared__ u16 As[64*64];
  __shared__ u16 Bs[64*64];
  __shared__ float gs[64*64];
  int tid=threadIdx.x, lane=tid&63, w=tid>>6;
  int bm=blockIdx.y*64, bn=blockIdx.x*64;
  int wm=(w&1)*32, wn=(w>>1)*32;
  f32x4 acc[2][2];
#pragma unroll
  for(int i=0;i<2;i++)
#pragma unroll
    for(int j=0;j<2;j++) acc[i][j]=(f32x4)(0.f);
  for(int k0=0;k0<H_;k0+=64){
    stage<64,0>(hh + (size_t)slotAbs*H_, 2, SP1*H_, k0, bm, 0, As, tid);
    stage<64,1>(Whh,                     m, H_,     k0, bn, 0, Bs, tid);
    __syncthreads();
#pragma unroll
    for(int kk=0;kk<2;kk++){
      f16x8 af[2], bq[2];
#pragma unroll
      for(int i=0;i<2;i++) af[i]=frag_ld(As, wm+i*16, kk*4, lane);
#pragma unroll
      for(int j=0;j<2;j++) bq[j]=frag_ld(Bs, wn+j*16, kk*4, lane);
#pragma unroll
      for(int i=0;i<2;i++)
#pragma unroll
        for(int j=0;j<2;j++)
          acc[i][j]=__builtin_amdgcn_mfma_f32_16x16x32_f16(af[i],bq[j],acc[i][j],0,0,0);
    }
    __syncthreads();
  }
  int rl=lane>>4, cl=lane&15;
#pragma unroll
  for(int j=0;j<2;j++){
    int coll=wn+j*16+cl;
#pragma unroll
    for(int i=0;i<2;i++){
#pragma unroll
      for(int r=0;r<4;r++){
        int rowl=wm+i*16+rl*4+r;
        float xv=(float)((const _Float16*)xg)[((size_t)(bm+rowl)*CH_+dt)*G_ + bn+coll];
        gs[rowl*64+coll]=acc[i][j][r] + xv;
      }
    }
  }
  __syncthreads();
#pragma unroll
  for(int p=0;p<4;p++){
    int idx=p*256+tid;
    int rowl=idx>>4, u=idx&15;
    float4 gv = *(const float4*)&gs[rowl*64+u*4];
    float ii=1.f/(1.f+__expf(-gv.x));
    float ff=1.f/(1.f+__expf(-gv.y));
    float gg=1.f-2.f/(__expf(2.f*gv.z)+1.f);
    float oo=1.f/(1.f+__expf(-gv.w));
    int gb=bm+rowl;
    int gu=(bn>>2)+u;
    size_t ci=(size_t)gb*H_+gu;
    float cn=ff*cst[ci]+ii*gg;
    cst[ci]=cn;
    float th=1.f-2.f/(__expf(2.f*cn)+1.f);
    hh[((size_t)gb*SP1 + slotAbs+1)*H_ + gu]=f2h(oo*th);
  }
}

// ---- heads as MFMA GEMM + fused log-softmax. Block: 128 rows x 32 cols, 512 thr.
// WH fp16 [32][1024]: rows 0-17 W_l, 18 W_v, 19-31 zero. Grid M_/128 = 256 blocks.
__global__ __launch_bounds__(512,1) void heads_gemm(const u16* __restrict__ hh,
      const u16* __restrict__ WH, const float* __restrict__ blf,
      const int* __restrict__ acts, void* __restrict__ out, const int* __restrict__ flag){
  int m=*flag;
  __shared__ u16 Bs[16*2048];     // 64 KB WH, 16 k-tiles [32][64] swizzled
  __shared__ u16 As[128*64];      // 16 KB A tile
  __shared__ float gs[128*36];    // 18.4 KB logits
  int tid=threadIdx.x, lane=tid&63, w=tid>>6;
  int bm=blockIdx.x*128;          // rg base
  // WH -> Bs (reg-staged, swizzled)
#pragma unroll
  for(int i=0;i<8;i++){
    int s=tid+i*512;              // chunk 0..4095
    int kt=s>>8, r=(s>>3)&31, gc=s&7, lc=gc^(r&7);
    *(f16x8*)(Bs+kt*2048+r*64+lc*8) = *(const f16x8*)(WH + (size_t)r*H_ + kt*64 + gc*8);
  }
  f32x4 acc0=(f32x4)(0.f), acc1=(f32x4)(0.f);
  for(int kt=0;kt<16;kt++){
    // stage A[128][64]: 1024 slots, 512 thr -> 2 gload_lds each
#pragma unroll
    for(int i=0;i<2;i++){
      int s0=i*512+(w<<6), s=s0+lane;
      int r=s>>3, gc=(s&7)^(r&7);
      int rg=bm+r;
      const u16* src=hh + ((size_t)(rg>>7)*SP1 + (rg&127)+1)*H_ + kt*64 + gc*8;
      u16* dst=As + s0*8;          // wave-uniform; HW adds lane*16B
      __builtin_amdgcn_global_load_lds((const __attribute__((address_space(1))) unsigned int*)src,
                                       (__attribute__((address_space(3))) unsigned int*)dst,
                                       16, 0, 0);
    }
    __syncthreads();               // As ready (+Bs on kt=0)
#pragma unroll
    for(int kk=0;kk<2;kk++){
      f16x8 af=frag_ld(As, w*16, kk*4, lane);
      f16x8 b0=frag_ld(Bs+kt*2048, 0,  kk*4, lane);
      f16x8 b1=frag_ld(Bs+kt*2048, 16, kk*4, lane);
      acc0=__builtin_amdgcn_mfma_f32_16x16x32_f16(af,b0,acc0,0,0,0);
      acc1=__builtin_amdgcn_mfma_f32_16x16x32_f16(af,b1,acc1,0,0,0);
    }
    __syncthreads();
  }
  // park logits in LDS: row = w*16+(lane>>4)*4+r, col = c*16+(lane&15)
#pragma unroll
  for(int r=0;r<4;r++){
    gs[(w*16+(lane>>4)*4+r)*36 + (lane&15)]      = acc0[r];
    gs[(w*16+(lane>>4)*4+r)*36 + 16 + (lane&15)] = acc1[r];
  }
  __syncthreads();
  // finish: 128 threads, one row each
  if(tid<128){
    int rg=bm+tid;
    float lg[18];
#pragma unroll
    for(int j=0;j<18;j++) lg[j]=gs[tid*36+j]+blf[j];
    float value=gs[tid*36+18]+blf[18];
    float mx=lg[0];
#pragma unroll
    for(int j=1;j<18;j++) mx=fmaxf(mx,lg[j]);
    float se=0.f, s1=0.f;
#pragma unroll
    for(int j=0;j<18;j++){ float e=__expf(lg[j]-mx); se+=e; s1+=e*(lg[j]-mx); }
    float lse=__logf(se);
    int a=acts[rg];
    float la=0.f;
#pragma unroll
    for(int j=0;j<18;j++) la = (j==a) ? lg[j] : la;   // no dynamic reg index
    float lp=la-mx-lse;
    float ent=lse - s1/se;
    if(m){
      ((float*)out)[rg]=lp; ((float*)out)[M_+rg]=ent; ((float*)out)[2*M_+rg]=value;
    } else {
      ((u16*)out)[rg]=f2bf(lp); ((u16*)out)[M_+rg]=f2bf(ent); ((u16*)out)[2*M_+rg]=f2bf(value);
    }
  }
}

// ---- fallback heads (no-WH tier): wave per row, shuffle-reduce dots.
__global__ __launch_bounds__(256,2) void heads_full(const u16* __restrict__ hh,
      const void* __restrict__ Wl, const void* __restrict__ Wv,
      const float* __restrict__ blf, const int* __restrict__ acts,
      void* __restrict__ out, const int* __restrict__ flag){
  int m=*flag;
  int rg = blockIdx.x*4 + (threadIdx.x>>6);
  int lane = threadIdx.x & 63;
  int b=rg>>7, t=rg&(S_-1);
  const u16* h = hh + ((size_t)b*SP1 + t+1)*H_;
  f16x8 h0=*(const f16x8*)(h + lane*16), h1=*(const f16x8*)(h + lane*16 + 8);
  float hv[16];
#pragma unroll
  for(int k=0;k<8;k++){ hv[k]=(float)h0[k]; hv[8+k]=(float)h1[k]; }
  float dots[19];
#pragma unroll
  for(int j=0;j<19;j++){
    const void* wrow = (j<18) ? Wl : Wv;
    size_t roff = (j<18) ? (size_t)j*H_ : 0;
    float wv_[16];
    if(m){
      const float* f=(const float*)wrow + roff + lane*16;
      float4 a=*(const float4*)f, b2=*(const float4*)(f+4), c=*(const float4*)(f+8), d=*(const float4*)(f+12);
      wv_[0]=a.x;wv_[1]=a.y;wv_[2]=a.z;wv_[3]=a.w; wv_[4]=b2.x;wv_[5]=b2.y;wv_[6]=b2.z;wv_[7]=b2.w;
      wv_[8]=c.x;wv_[9]=c.y;wv_[10]=c.z;wv_[11]=c.w; wv_[12]=d.x;wv_[13]=d.y;wv_[14]=d.z;wv_[15]=d.w;
    } else {
      const u16* ub=(const u16*)wrow + roff + lane*16;
      s16x8 w0=*(const s16x8*)ub, w1=*(const s16x8*)(ub+8);
#pragma unroll
      for(int k=0;k<8;k++){ wv_[k]=bf2f((u16)w0[k]); wv_[8+k]=bf2f((u16)w1[k]); }
    }
    float d=0.f;
#pragma unroll
    for(int k=0;k<16;k++) d += hv[k]*wv_[k];
#pragma unroll
    for(int mm=1;mm<64;mm<<=1) d += __shfl_xor(d, mm, 64);
    dots[j]=d;
  }
  float lg[18];
#pragma unroll
  for(int j=0;j<18;j++) lg[j]=dots[j]+blf[j];
  float value=dots[18]+blf[18];
  float mx=lg[0];
#pragma unroll
  for(int j=1;j<18;j++) mx=fmaxf(mx,lg[j]);
  float se=0.f, s1=0.f;
#pragma unroll
  for(int j=0;j<18;j++){ float e=__expf(lg[j]-mx); se+=e; s1+=e*(lg[j]-mx); }
  float lse=__logf(se);
  int a=acts[rg];
  float la=0.f;
#pragma unroll
  for(int j=0;j<18;j++) la = (j==a) ? lg[j] : la;
  float lp=la-mx-lse;
  float ent=lse - s1/se;
  if(lane==0){
    if(m){
      ((float*)out)[rg]=lp; ((float*)out)[M_+rg]=ent; ((float*)out)[2*M_+rg]=value;
    } else {
      ((u16*)out)[rg]=f2bf(lp); ((u16*)out)[M_+rg]=f2bf(ent); ((u16*)out)[2*M_+rg]=f2bf(value);
    }
  }
}

// ---- dtype detect
__global__ void detect(const u16* __restrict__ obs_w, int* __restrict__ flag){
  __shared__ float red[256];
  float mx=0.f;
  for(int i=threadIdx.x;i<4096;i+=256) mx=fmaxf(mx,fabsf(bf2f(obs_w[i])));
  red[threadIdx.x]=mx; __syncthreads();
  for(int s=128;s>0;s>>=1){
    if(threadIdx.x<s) red[threadIdx.x]=fmaxf(red[threadIdx.x],red[threadIdx.x+s]);
    __syncthreads();
  }
  if(threadIdx.x==0) *flag=(red[0]>1e4f)?1:0;
}

// ---- prep: biases, c state, h seed (fp16, slot 0), zero barrier flags.
__global__ void prep(const void* bih, const void* bhh, const void* b1, const void* bl, const void* bv,
                     const void* cx, const void* hx,
                     float* biasg, float* b1f, float* blf, float* cst, u16* hh,
                     int* cnt, const int* __restrict__ flag){
  int m=*flag;
  size_t i=(size_t)blockIdx.x*256+threadIdx.x;
  if(i<G_){ size_t rm=(i&3)*H_+(i>>2); biasg[i]=ldf(bih,rm,m)+ldf(bhh,rm,m); return; }
  i-=G_;
  if(i<H_){ b1f[i]=ldf(b1,i,m); return; }
  i-=H_;
  if(i<19){ blf[i]=(i<18)?ldf(bl,i,m):ldf(bv,0,m); return; }
  i-=19;
  if(i<512){ cnt[i]=0; return; }
  i-=512;
  if(i<(size_t)B_*H_){ cst[i]=ldf(cx,i,m); return; }
  i-=(size_t)B_*H_;
  if(i<(size_t)B_*H_){
    size_t b=i>>10, k=i&1023;
    hh[b*(SP1*H_) + k]=f2h(ldf(hx,i,m));   // seed at slot 0
  }
}

// ---- weight pre-conversion to fp16: W1, gate-permuted Wih/Whh, packed heads WH[32][1024].
__global__ void convw(const void* W1, const void* Wih, const void* Whh,
                      const void* Wl, const void* Wv,
                      u16* W1h, u16* Wihp, u16* Whhp, u16* WH,
                      const int* __restrict__ flag){
  int m=*flag;
  size_t i=((size_t)blockIdx.x*256+threadIdx.x)*8;
  const size_t n1=(size_t)H_*F_, n2=(size_t)G_*H_, n3=(size_t)32*H_;
  if(i<n1){ *(f16x8*)(W1h+i)=load8_h(W1,i,m); return; }
  i-=n1;
  if(i<n2){ size_t p=i>>10, c=i&1023; size_t sr=(p&3)*H_+(p>>2);
            *(f16x8*)(Wihp+i)=load8_h(Wih, sr*H_+c, m); return; }
  i-=n2;
  if(i<n2){ size_t p=i>>10, c=i&1023; size_t sr=(p&3)*H_+(p>>2);
            *(f16x8*)(Whhp+i)=load8_h(Whh, sr*H_+c, m); return; }
  i-=n2;
  if(i<n3){
    size_t j=i>>10, c=i&1023;
    f16x8 v;
    if(j<18)      v=load8_h(Wl, j*H_+c, m);
    else if(j==18) v=load8_h(Wv, c, m);
    else{ for(int k=0;k<8;k++) v[k]=(_Float16)0.f; }
    *(f16x8*)(WH+i)=v;
  }
}
__global__ void convobs(const void* obs, u16* obsh, const int* __restrict__ flag){
  int m=*flag;
  size_t i=((size_t)blockIdx.x*256+threadIdx.x)*8;
  if(i<(size_t)M_*F_) *(f16x8*)(obsh+i)=load8_h(obs,i,m);
}

extern "C" void kernel_launch(void* const* d_in, const int* in_sizes, int n_in,
                              void* d_out, int out_size, void* d_ws, size_t ws_size,
                              hipStream_t stream){
  const void* obs=d_in[0];
  const void* hx =d_in[1];
  const void* cx =d_in[2];
  const int* acts=(const int*)d_in[3];
  const void* W1 =d_in[4];
  const void* b1 =d_in[5];
  const void* Wih=d_in[6];
  const void* bih=d_in[7];
  const void* Whh=d_in[8];
  const void* bhh=d_in[9];
  const void* Wv =d_in[10];
  const void* bv =d_in[11];
  const void* Wl =d_in[12];
  const void* bl =d_in[13];

  char* w=(char*)d_ws;
  auto alloc=[&](size_t n){ char* p=w; w+=((n+255)&~(size_t)255); return p; };
  int*   flag =(int*)alloc(4);
  int*   cnt  =(int*)alloc(512*4);
  float* biasg=(float*)alloc((size_t)G_*4);
  float* b1f  =(float*)alloc((size_t)H_*4);
  float* blf  =(float*)alloc(32*4);
  float* cst  =(float*)alloc((size_t)B_*H_*4);     // 1 MB fp32 c
  u16*   hh   =(u16*)alloc((size_t)B_*SP1*H_*2);   // 67.6 MB fp16 full h history
  u16*   xc   =(u16*)alloc((size_t)CR_*H_*2);      // 8 MB fp16 x chunk
  u16*   xg   =(u16*)alloc((size_t)CR_*G_*2);      // 32 MB fp16 xg chunk
  // tiers
  size_t nW=((size_t)H_*F_ + 2*(size_t)G_*H_ + 32*(size_t)H_)*2 + 1024;
  bool pathW = ((size_t)(w-(char*)d_ws) + nW) <= ws_size;
  u16 *W1h=0,*Wihp=0,*Whhp=0,*WH=0;
  if(pathW){ W1h=(u16*)alloc((size_t)H_*F_*2); Wihp=(u16*)alloc((size_t)G_*H_*2);
             Whhp=(u16*)alloc((size_t)G_*H_*2); WH=(u16*)alloc((size_t)32*H_*2); }
  size_t nXC=(size_t)M_*H_*2 + 256;
  bool pathXC = pathW && (((size_t)(w-(char*)d_ws) + nXC) <= ws_size);
  u16* xcf=0; if(pathXC) xcf=(u16*)alloc((size_t)M_*H_*2);
  size_t nO=(size_t)M_*F_*2 + 256;
  bool pathO = pathXC && (((size_t)(w-(char*)d_ws) + nO) <= ws_size);
  u16* obsh=0; if(pathO) obsh=(u16*)alloc((size_t)M_*F_*2);

  detect<<<1,256,0,stream>>>((const u16*)obs, flag);
  {
    int total=G_+H_+19+512+B_*H_+B_*H_;
    prep<<<(total+255)/256,256,0,stream>>>(bih,bhh,b1,bl,bv,cx,hx, biasg,b1f,blf,cst,hh,cnt, flag);
  }
  if(pathW){
    size_t n=((size_t)H_*F_+2*(size_t)G_*H_+32*(size_t)H_)/8;
    convw<<<(int)((n+255)/256),256,0,stream>>>(W1,Wih,Whh,Wl,Wv, W1h,Wihp,Whhp,WH, flag);
  }
  if(pathO){
    size_t n=(size_t)M_*F_/8;
    convobs<<<(int)((n+255)/256),256,0,stream>>>(obs, obsh, flag);
  }
  if(pathXC){
    gemm128<0,0,0><<<dim3(H_/128, M_/128),256,0,stream>>>(
        pathO?(const void*)obsh:obs, pathW?(const void*)W1h:W1, xcf, b1f, flag,
        F_, F_, F_, H_, 0, pathO?2:-1, pathW?2:-1);
  }

  const int NC=S_/CH_;
  for(int c=0;c<NC;c++){
    int t0=c*CH_;
    if(!pathXC){
      gemm128<2,0,0><<<dim3(H_/128, CR_/128),256,0,stream>>>(
          obs, pathW?(const void*)W1h:W1, xc, b1f, flag, F_, F_, F_, H_, t0, -1, pathW?2:-1);
    }
    if(pathXC)
      gemm128<2,0,2><<<dim3(G_/128, CR_/128),256,0,stream>>>(
          xcf, Wihp, xg, biasg, flag, H_, H_, H_, G_, t0, 2, 2);
    else if(pathW)
      gemm128<0,0,2><<<dim3(G_/128, CR_/128),256,0,stream>>>(
          xc, Wihp, xg, biasg, flag, H_, H_, H_, G_, 0, 2, 2);
    else
      gemm128<0,1,2><<<dim3(G_/128, CR_/128),256,0,stream>>>(
          xc, Wih, xg, biasg, flag, H_, H_, H_, G_, 0, 2, -1);

    if(pathW)
      lstm_persist<<<256,512,0,stream>>>(hh, Whhp, xg, cst, cnt, t0);
    else
      for(int dt=0;dt<CH_;dt++)
        lstm_step<<<dim3(G_/64, B_/64),256,0,stream>>>(hh, t0+dt, dt, Whh, xg, cst, flag);
  }

  if(pathW)
    heads_gemm<<<dim3(M_/128),512,0,stream>>>(hh, WH, blf, acts, d_out, flag);
  else
    heads_full<<<dim3(M_/4),256,0,stream>>>(hh, Wl, Wv, blf, acts, d_out, flag);
}